// Round 1
// baseline (2217.930 us; speedup 1.0000x reference)
//
#include <hip/hip_runtime.h>

#define NMF_EPS 1e-6f

constexpr int BM = 64, BN = 64, BK = 16;

// Templated tiled fp32 GEMM.
// ALAY: 0 = A is row-major [M,K] (lda = stride between m-rows)
//       1 = A is stored [K,M], m fastest (lda = stride between k-rows)
// BLAY: 0 = B is stored [K,N], n fastest (ldb = stride between k-rows)
//       1 = B is stored [N,K], k fastest (ldb = stride between n-rows)
// EPI:  0 = plain store
//       1 = atomicAdd (split-K accumulate; C must be pre-zeroed)
//       2 = relu(acc + bias[m])
//       3 = relu(ham*acc + sc*res[m,n])   (res has layout of C)
template<int ALAY, int BLAY, int EPI>
__global__ __launch_bounds__(256) void gemm_kernel(
    const float* __restrict__ A, const float* __restrict__ B, float* __restrict__ C,
    int Kchunk, int kchunks,
    int lda, int ldb, int ldc,
    long sA, long sB, long sC,
    const float* __restrict__ bias,
    const float* __restrict__ res, long sRes,
    const float* __restrict__ hamp, const float* __restrict__ scp)
{
    __shared__ float As[BK][BM + 4];
    __shared__ float Bs[BK][BN + 4];

    const int bz    = blockIdx.z;
    const int batch = bz / kchunks;
    const int kc    = bz - batch * kchunks;
    const int k0    = kc * Kchunk;

    const float* Ab = A + (long)batch * sA;
    const float* Bb = B + (long)batch * sB;
    float*       Cb = C + (long)batch * sC;

    const int m0  = blockIdx.y * BM;
    const int n0  = blockIdx.x * BN;
    const int tid = threadIdx.x;
    const int ty  = tid >> 4, tx = tid & 15;

    float acc[4][4] = {};

    for (int kt = 0; kt < Kchunk; kt += BK) {
        // ---- load A tile -> As[k][m]
        if (ALAY == 0) {
            const int m = tid >> 2, k4 = (tid & 3) << 2;
            float4 v = *(const float4*)&Ab[(long)(m0 + m) * lda + (k0 + kt + k4)];
            As[k4 + 0][m] = v.x; As[k4 + 1][m] = v.y;
            As[k4 + 2][m] = v.z; As[k4 + 3][m] = v.w;
        } else {
            const int k = tid >> 4, m4 = (tid & 15) << 2;
            float4 v = *(const float4*)&Ab[(long)(k0 + kt + k) * lda + (m0 + m4)];
            *(float4*)&As[k][m4] = v;
        }
        // ---- load B tile -> Bs[k][n]
        if (BLAY == 0) {
            const int k = tid >> 4, n4 = (tid & 15) << 2;
            float4 v = *(const float4*)&Bb[(long)(k0 + kt + k) * ldb + (n0 + n4)];
            *(float4*)&Bs[k][n4] = v;
        } else {
            const int n = tid >> 2, k4 = (tid & 3) << 2;
            float4 v = *(const float4*)&Bb[(long)(n0 + n) * ldb + (k0 + kt + k4)];
            Bs[k4 + 0][n] = v.x; Bs[k4 + 1][n] = v.y;
            Bs[k4 + 2][n] = v.z; Bs[k4 + 3][n] = v.w;
        }
        __syncthreads();
        #pragma unroll
        for (int k = 0; k < BK; ++k) {
            float4 a4 = *(const float4*)&As[k][ty << 2];
            float4 b4 = *(const float4*)&Bs[k][tx << 2];
            float av[4] = {a4.x, a4.y, a4.z, a4.w};
            float bv[4] = {b4.x, b4.y, b4.z, b4.w};
            #pragma unroll
            for (int i = 0; i < 4; ++i)
                #pragma unroll
                for (int j = 0; j < 4; ++j)
                    acc[i][j] = fmaf(av[i], bv[j], acc[i][j]);
        }
        __syncthreads();
    }

    const int mb = m0 + (ty << 2), nb = n0 + (tx << 2);
    if (EPI == 1) {
        #pragma unroll
        for (int i = 0; i < 4; ++i)
            #pragma unroll
            for (int j = 0; j < 4; ++j)
                atomicAdd(&Cb[(long)(mb + i) * ldc + nb + j], acc[i][j]);
    } else {
        float hm = 1.f, sc = 0.f;
        if (EPI == 3) { hm = *hamp; sc = *scp; }
        #pragma unroll
        for (int i = 0; i < 4; ++i) {
            float4 o = make_float4(acc[i][0], acc[i][1], acc[i][2], acc[i][3]);
            if (EPI == 2) {
                float bvv = bias[mb + i];
                o.x = fmaxf(o.x + bvv, 0.f); o.y = fmaxf(o.y + bvv, 0.f);
                o.z = fmaxf(o.z + bvv, 0.f); o.w = fmaxf(o.w + bvv, 0.f);
            }
            if (EPI == 3) {
                float4 r = *(const float4*)&res[(long)batch * sRes + (long)(mb + i) * ldc + nb];
                o.x = fmaxf(fmaf(hm, o.x, sc * r.x), 0.f);
                o.y = fmaxf(fmaf(hm, o.y, sc * r.y), 0.f);
                o.z = fmaxf(fmaf(hm, o.z, sc * r.z), 0.f);
                o.w = fmaxf(fmaf(hm, o.w, sc * r.w), 0.f);
            }
            *(float4*)&Cb[(long)(mb + i) * ldc + nb] = o;
        }
    }
}

// bases[b,:,r] = bases0[b,:,r] / max(||bases0[b,:,r]||_2, 1e-12); D=512, R=64
__global__ void l2norm_kernel(const float* __restrict__ b0, float* __restrict__ bases,
                              int D, int R)
{
    const int b = blockIdx.x;
    const int r = threadIdx.x;
    const float* src = b0 + (long)b * D * R;
    float* dst = bases + (long)b * D * R;
    float s = 0.f;
    for (int d = 0; d < D; ++d) { float v = src[d * R + r]; s = fmaf(v, v, s); }
    float inv = 1.0f / fmaxf(sqrtf(s), 1e-12f);
    for (int d = 0; d < D; ++d) dst[d * R + r] = src[d * R + r] * inv;
}

// coef[row, r] = softmax over r (R=64) of xtb[row, r]; one wave per row
__global__ __launch_bounds__(256) void softmax_kernel(const float* __restrict__ xtb,
                                                      float* __restrict__ coef)
{
    const long row = (long)blockIdx.x * 4 + (threadIdx.x >> 6);
    const int lane = threadIdx.x & 63;
    float v = xtb[row * 64 + lane];
    float m = v;
    #pragma unroll
    for (int off = 32; off; off >>= 1) m = fmaxf(m, __shfl_xor(m, off, 64));
    float e = __expf(v - m);
    float s = e;
    #pragma unroll
    for (int off = 32; off; off >>= 1) s += __shfl_xor(s, off, 64);
    coef[row * 64 + lane] = e / s;
}

// Multiplicative update (used for both coef and bases):
//   T[row, r] = T[row, r] * Num[row, r] / (sum_s T[row, s] * G[s, r] + EPS)
// G is [64,64] per batch (btb or ctc). One wave per row; G staged in LDS.
__global__ __launch_bounds__(256) void mu_update_kernel(
    float* __restrict__ T, const float* __restrict__ Num, const float* __restrict__ G,
    int rows_per_batch)
{
    __shared__ float Gl[64 * 64];
    const int b   = blockIdx.y;
    const int tid = threadIdx.x;
    const float* Gb = G + (long)b * 4096;
    for (int i = tid; i < 4096; i += 256) Gl[i] = Gb[i];
    __syncthreads();
    const int wave = tid >> 6, lane = tid & 63;
    const long row = (long)b * rows_per_batch + (long)blockIdx.x * 4 + wave;
    const float c = T[row * 64 + lane];
    const float t = Num[row * 64 + lane];
    float denom = 0.f;
    #pragma unroll 8
    for (int s = 0; s < 64; ++s) {
        float cs = __shfl(c, s, 64);
        denom = fmaf(cs, Gl[s * 64 + lane], denom);
    }
    T[row * 64 + lane] = c * t / (denom + NMF_EPS);
}

extern "C" void kernel_launch(void* const* d_in, const int* in_sizes, int n_in,
                              void* d_out, int out_size, void* d_ws, size_t ws_size,
                              hipStream_t stream)
{
    const float* x_in     = (const float*)d_in[0]; // [8,512,64,64]
    const float* bases0   = (const float*)d_in[1]; // [8,512,64]
    const float* w_lower  = (const float*)d_in[2]; // [512,512]
    const float* b_lower  = (const float*)d_in[3];
    const float* w_cheese = (const float*)d_in[4];
    const float* b_cheese = (const float*)d_in[5];
    const float* w_upper  = (const float*)d_in[6];
    const float* csc      = (const float*)d_in[7]; // coef_shortcut
    const float* cham     = (const float*)d_in[8]; // coef_ham
    float* out = (float*)d_out;

    const int B = 8, C = 512, N = 4096, R = 64;

    float* ws    = (float*)d_ws;
    float* Xb    = ws;                       // [B,C,N] lower output / NMF "x" (later cheese out)
    float* Zb    = Xb   + (long)B * C * N;   // [B,C,N] ham reconstruction
    float* coef  = Zb   + (long)B * C * N;   // [B,N,R]
    float* xtb   = coef + (long)B * N * R;   // [B,N,R]
    float* bases = xtb  + (long)B * N * R;   // [B,C,R]
    float* xc    = bases + (long)B * C * R;  // [B,C,R]
    float* btb   = xc   + (long)B * C * R;   // [B,R,R]
    float* ctc   = btb  + (long)B * R * R;   // [B,R,R]

    const long sCN = (long)C * N, sNR = (long)N * R, sCR = (long)C * R, sRR = (long)R * R;
    const dim3 blk(256);

    // bases = l2norm(bases0, axis=D)
    l2norm_kernel<<<dim3(B), dim3(R), 0, stream>>>(bases0, bases, C, R);

    // Xb = relu(w_lower @ x + b_lower)
    gemm_kernel<0, 0, 2><<<dim3(N / BN, C / BM, B), blk, 0, stream>>>(
        w_lower, x_in, Xb, C, 1, C, N, N, 0L, sCN, sCN,
        b_lower, nullptr, 0L, nullptr, nullptr);

    // xtb = X^T @ bases ; coef = softmax_r(xtb)
    gemm_kernel<1, 0, 0><<<dim3(R / BN, N / BM, B), blk, 0, stream>>>(
        Xb, bases, xtb, C, 1, N, R, R, sCN, sCR, sNR,
        nullptr, nullptr, 0L, nullptr, nullptr);
    softmax_kernel<<<dim3(B * N / 4), blk, 0, stream>>>(xtb, coef);

    for (int step = 0; step < 6; ++step) {
        // xtb = X^T @ bases
        gemm_kernel<1, 0, 0><<<dim3(R / BN, N / BM, B), blk, 0, stream>>>(
            Xb, bases, xtb, C, 1, N, R, R, sCN, sCR, sNR,
            nullptr, nullptr, 0L, nullptr, nullptr);
        // btb = bases^T @ bases  (split-K=8, atomic)
        hipMemsetAsync(btb, 0, (size_t)B * R * R * sizeof(float), stream);
        gemm_kernel<1, 0, 1><<<dim3(1, 1, B * 8), blk, 0, stream>>>(
            bases, bases, btb, C / 8, 8, R, R, R, sCR, sCR, sRR,
            nullptr, nullptr, 0L, nullptr, nullptr);
        // coef = coef * xtb / (coef @ btb + eps)
        mu_update_kernel<<<dim3(N / 4, B), blk, 0, stream>>>(coef, xtb, btb, N);
        // xc = X @ coef  (split-K=8, atomic)
        hipMemsetAsync(xc, 0, (size_t)B * C * R * sizeof(float), stream);
        gemm_kernel<0, 0, 1><<<dim3(1, C / BM, B * 8), blk, 0, stream>>>(
            Xb, coef, xc, N / 8, 8, N, R, R, sCN, sNR, sCR,
            nullptr, nullptr, 0L, nullptr, nullptr);
        // ctc = coef^T @ coef  (split-K=32, atomic)
        hipMemsetAsync(ctc, 0, (size_t)B * R * R * sizeof(float), stream);
        gemm_kernel<1, 0, 1><<<dim3(1, 1, B * 32), blk, 0, stream>>>(
            coef, coef, ctc, N / 32, 32, R, R, R, sNR, sNR, sRR,
            nullptr, nullptr, 0L, nullptr, nullptr);
        // bases = bases * xc / (bases @ ctc + eps)
        mu_update_kernel<<<dim3(C / 4, B), blk, 0, stream>>>(bases, xc, ctc, C);
    }

    // final differentiable coef refinement
    gemm_kernel<1, 0, 0><<<dim3(R / BN, N / BM, B), blk, 0, stream>>>(
        Xb, bases, xtb, C, 1, N, R, R, sCN, sCR, sNR,
        nullptr, nullptr, 0L, nullptr, nullptr);
    hipMemsetAsync(btb, 0, (size_t)B * R * R * sizeof(float), stream);
    gemm_kernel<1, 0, 1><<<dim3(1, 1, B * 8), blk, 0, stream>>>(
        bases, bases, btb, C / 8, 8, R, R, R, sCR, sCR, sRR,
        nullptr, nullptr, 0L, nullptr, nullptr);
    mu_update_kernel<<<dim3(N / 4, B), blk, 0, stream>>>(coef, xtb, btb, N);

    // Zb = bases @ coef^T
    gemm_kernel<0, 1, 0><<<dim3(N / BN, C / BM, B), blk, 0, stream>>>(
        bases, coef, Zb, R, 1, R, R, N, sCR, sNR, sCN,
        nullptr, nullptr, 0L, nullptr, nullptr);

    // Xb = relu(w_cheese @ Zb + b_cheese)   (Xb no longer needed as NMF input)
    gemm_kernel<0, 0, 2><<<dim3(N / BN, C / BM, B), blk, 0, stream>>>(
        w_cheese, Zb, Xb, C, 1, C, N, N, 0L, sCN, sCN,
        b_cheese, nullptr, 0L, nullptr, nullptr);

    // out = relu(coef_ham * (w_upper @ Xb) + coef_shortcut * x)
    gemm_kernel<0, 0, 3><<<dim3(N / BN, C / BM, B), blk, 0, stream>>>(
        w_upper, Xb, out, C, 1, C, N, N, 0L, sCN, sCN,
        nullptr, x_in, sCN, cham, csc);
}

// Round 2
// 2004.994 us; speedup vs baseline: 1.1062x; 1.1062x over previous
//
#include <hip/hip_runtime.h>

#define NMF_EPS 1e-6f

constexpr int BM = 64, BN = 64, BK = 16;

// Templated tiled fp32 GEMM.
// ALAY: 0 = A is row-major [M,K] (lda = stride between m-rows)
//       1 = A is stored [K,M], m fastest (lda = stride between k-rows)
// BLAY: 0 = B is stored [K,N], n fastest (ldb = stride between k-rows)
//       1 = B is stored [N,K], k fastest (ldb = stride between n-rows)
// EPI:  0 = plain store
//       1 = atomicAdd (split-K accumulate; C must be pre-zeroed)
//       2 = relu(acc + bias[m])
//       3 = relu(ham*acc + sc*res[m,n])   (res has layout of C)
template<int ALAY, int BLAY, int EPI>
__global__ __launch_bounds__(256) void gemm_kernel(
    const float* __restrict__ A, const float* __restrict__ B, float* __restrict__ C,
    int Kchunk, int kchunks,
    int lda, int ldb, int ldc,
    long sA, long sB, long sC,
    const float* __restrict__ bias,
    const float* __restrict__ res, long sRes,
    const float* __restrict__ hamp, const float* __restrict__ scp)
{
    __shared__ float As[BK][BM + 4];
    __shared__ float Bs[BK][BN + 4];

    const int bz    = blockIdx.z;
    const int batch = bz / kchunks;
    const int kc    = bz - batch * kchunks;
    const int k0    = kc * Kchunk;

    const float* Ab = A + (long)batch * sA;
    const float* Bb = B + (long)batch * sB;
    float*       Cb = C + (long)batch * sC;

    const int m0  = blockIdx.y * BM;
    const int n0  = blockIdx.x * BN;
    const int tid = threadIdx.x;
    const int ty  = tid >> 4, tx = tid & 15;

    float acc[4][4] = {};

    for (int kt = 0; kt < Kchunk; kt += BK) {
        // ---- load A tile -> As[k][m]
        if (ALAY == 0) {
            const int m = tid >> 2, k4 = (tid & 3) << 2;
            float4 v = *(const float4*)&Ab[(long)(m0 + m) * lda + (k0 + kt + k4)];
            As[k4 + 0][m] = v.x; As[k4 + 1][m] = v.y;
            As[k4 + 2][m] = v.z; As[k4 + 3][m] = v.w;
        } else {
            const int k = tid >> 4, m4 = (tid & 15) << 2;
            float4 v = *(const float4*)&Ab[(long)(k0 + kt + k) * lda + (m0 + m4)];
            *(float4*)&As[k][m4] = v;
        }
        // ---- load B tile -> Bs[k][n]
        if (BLAY == 0) {
            const int k = tid >> 4, n4 = (tid & 15) << 2;
            float4 v = *(const float4*)&Bb[(long)(k0 + kt + k) * ldb + (n0 + n4)];
            *(float4*)&Bs[k][n4] = v;
        } else {
            const int n = tid >> 2, k4 = (tid & 3) << 2;
            float4 v = *(const float4*)&Bb[(long)(n0 + n) * ldb + (k0 + kt + k4)];
            Bs[k4 + 0][n] = v.x; Bs[k4 + 1][n] = v.y;
            Bs[k4 + 2][n] = v.z; Bs[k4 + 3][n] = v.w;
        }
        __syncthreads();
        #pragma unroll
        for (int k = 0; k < BK; ++k) {
            float4 a4 = *(const float4*)&As[k][ty << 2];
            float4 b4 = *(const float4*)&Bs[k][tx << 2];
            float av[4] = {a4.x, a4.y, a4.z, a4.w};
            float bv[4] = {b4.x, b4.y, b4.z, b4.w};
            #pragma unroll
            for (int i = 0; i < 4; ++i)
                #pragma unroll
                for (int j = 0; j < 4; ++j)
                    acc[i][j] = fmaf(av[i], bv[j], acc[i][j]);
        }
        __syncthreads();
    }

    const int mb = m0 + (ty << 2), nb = n0 + (tx << 2);
    if (EPI == 1) {
        #pragma unroll
        for (int i = 0; i < 4; ++i)
            #pragma unroll
            for (int j = 0; j < 4; ++j)
                atomicAdd(&Cb[(long)(mb + i) * ldc + nb + j], acc[i][j]);
    } else {
        float hm = 1.f, sc = 0.f;
        if (EPI == 3) { hm = *hamp; sc = *scp; }
        #pragma unroll
        for (int i = 0; i < 4; ++i) {
            float4 o = make_float4(acc[i][0], acc[i][1], acc[i][2], acc[i][3]);
            if (EPI == 2) {
                float bvv = bias[mb + i];
                o.x = fmaxf(o.x + bvv, 0.f); o.y = fmaxf(o.y + bvv, 0.f);
                o.z = fmaxf(o.z + bvv, 0.f); o.w = fmaxf(o.w + bvv, 0.f);
            }
            if (EPI == 3) {
                float4 r = *(const float4*)&res[(long)batch * sRes + (long)(mb + i) * ldc + nb];
                o.x = fmaxf(fmaf(hm, o.x, sc * r.x), 0.f);
                o.y = fmaxf(fmaf(hm, o.y, sc * r.y), 0.f);
                o.z = fmaxf(fmaf(hm, o.z, sc * r.z), 0.f);
                o.w = fmaxf(fmaf(hm, o.w, sc * r.w), 0.f);
            }
            *(float4*)&Cb[(long)(mb + i) * ldc + nb] = o;
        }
    }
}

// bases[b,:,r] = bases0[b,:,r] / max(||bases0[b,:,r]||_2, 1e-12); D=512, R=64
// Parallel version: 1 block/batch, 1024 threads = 16 d-slices x 64 columns.
__global__ __launch_bounds__(1024) void l2norm_kernel(const float* __restrict__ b0,
                                                      float* __restrict__ bases)
{
    __shared__ float part[16][64];
    const int b = blockIdx.x;
    const int tid = threadIdx.x;
    const int r = tid & 63, slice = tid >> 6;     // 16 slices over D
    const float* src = b0 + (long)b * 512 * 64;
    float* dst = bases + (long)b * 512 * 64;
    float s = 0.f;
    #pragma unroll 4
    for (int d = slice; d < 512; d += 16) {
        float v = src[d * 64 + r];
        s = fmaf(v, v, s);
    }
    part[slice][r] = s;
    __syncthreads();
    if (slice == 0) {
        float t = 0.f;
        #pragma unroll
        for (int i = 0; i < 16; ++i) t += part[i][r];
        part[0][r] = 1.0f / fmaxf(sqrtf(t), 1e-12f);
    }
    __syncthreads();
    const float inv = part[0][r];
    #pragma unroll 4
    for (int d = slice; d < 512; d += 16)
        dst[d * 64 + r] = src[d * 64 + r] * inv;
}

// coef[row, r] = softmax over r (R=64) of xtb[row, r]; one wave per row
__global__ __launch_bounds__(256) void softmax_kernel(const float* __restrict__ xtb,
                                                      float* __restrict__ coef)
{
    const long row = (long)blockIdx.x * 4 + (threadIdx.x >> 6);
    const int lane = threadIdx.x & 63;
    float v = xtb[row * 64 + lane];
    float m = v;
    #pragma unroll
    for (int off = 32; off; off >>= 1) m = fmaxf(m, __shfl_xor(m, off, 64));
    float e = __expf(v - m);
    float s = e;
    #pragma unroll
    for (int off = 32; off; off >>= 1) s += __shfl_xor(s, off, 64);
    coef[row * 64 + lane] = e / s;
}

// Multiplicative update (used for both coef and bases):
//   T[row, r] = T[row, r] * Num[row, r] / (sum_s T[row, s] * G[s, r] + EPS)
// G is [64,64] per batch (btb or ctc). One wave per row; G staged in LDS.
__global__ __launch_bounds__(256) void mu_update_kernel(
    float* __restrict__ T, const float* __restrict__ Num, const float* __restrict__ G,
    int rows_per_batch)
{
    __shared__ float Gl[64 * 64];
    const int b   = blockIdx.y;
    const int tid = threadIdx.x;
    const float* Gb = G + (long)b * 4096;
    for (int i = tid; i < 4096; i += 256) Gl[i] = Gb[i];
    __syncthreads();
    const int wave = tid >> 6, lane = tid & 63;
    const long row = (long)b * rows_per_batch + (long)blockIdx.x * 4 + wave;
    const float c = T[row * 64 + lane];
    const float t = Num[row * 64 + lane];
    float denom = 0.f;
    #pragma unroll 8
    for (int s = 0; s < 64; ++s) {
        float cs = __shfl(c, s, 64);
        denom = fmaf(cs, Gl[s * 64 + lane], denom);
    }
    T[row * 64 + lane] = c * t / (denom + NMF_EPS);
}

extern "C" void kernel_launch(void* const* d_in, const int* in_sizes, int n_in,
                              void* d_out, int out_size, void* d_ws, size_t ws_size,
                              hipStream_t stream)
{
    const float* x_in     = (const float*)d_in[0]; // [8,512,64,64]
    const float* bases0   = (const float*)d_in[1]; // [8,512,64]
    const float* w_lower  = (const float*)d_in[2]; // [512,512]
    const float* b_lower  = (const float*)d_in[3];
    const float* w_cheese = (const float*)d_in[4];
    const float* b_cheese = (const float*)d_in[5];
    const float* w_upper  = (const float*)d_in[6];
    const float* csc      = (const float*)d_in[7]; // coef_shortcut
    const float* cham     = (const float*)d_in[8]; // coef_ham
    float* out = (float*)d_out;

    const int B = 8, C = 512, N = 4096, R = 64;

    float* ws    = (float*)d_ws;
    float* Xb    = ws;                       // [B,C,N] lower output / NMF "x" (later cheese out)
    float* Zb    = Xb   + (long)B * C * N;   // [B,C,N] ham reconstruction
    float* coef  = Zb   + (long)B * C * N;   // [B,N,R]
    float* xtb   = coef + (long)B * N * R;   // [B,N,R]
    float* bases = xtb  + (long)B * N * R;   // [B,C,R]
    float* xc    = bases + (long)B * C * R;  // [B,C,R]
    float* btb   = xc   + (long)B * C * R;   // [B,R,R]
    float* ctc   = btb  + (long)B * R * R;   // [B,R,R]

    const long sCN = (long)C * N, sNR = (long)N * R, sCR = (long)C * R, sRR = (long)R * R;
    const dim3 blk(256);

    // bases = l2norm(bases0, axis=D)
    l2norm_kernel<<<dim3(B), dim3(1024), 0, stream>>>(bases0, bases);

    // Xb = relu(w_lower @ x + b_lower)
    gemm_kernel<0, 0, 2><<<dim3(N / BN, C / BM, B), blk, 0, stream>>>(
        w_lower, x_in, Xb, C, 1, C, N, N, 0L, sCN, sCN,
        b_lower, nullptr, 0L, nullptr, nullptr);

    // xtb = X^T @ bases ; coef = softmax_r(xtb)
    gemm_kernel<1, 0, 0><<<dim3(R / BN, N / BM, B), blk, 0, stream>>>(
        Xb, bases, xtb, C, 1, N, R, R, sCN, sCR, sNR,
        nullptr, nullptr, 0L, nullptr, nullptr);
    softmax_kernel<<<dim3(B * N / 4), blk, 0, stream>>>(xtb, coef);

    for (int step = 0; step < 6; ++step) {
        // xtb = X^T @ bases
        gemm_kernel<1, 0, 0><<<dim3(R / BN, N / BM, B), blk, 0, stream>>>(
            Xb, bases, xtb, C, 1, N, R, R, sCN, sCR, sNR,
            nullptr, nullptr, 0L, nullptr, nullptr);
        // btb = bases^T @ bases  (split-K=8, atomic)
        hipMemsetAsync(btb, 0, (size_t)B * R * R * sizeof(float), stream);
        gemm_kernel<1, 0, 1><<<dim3(1, 1, B * 8), blk, 0, stream>>>(
            bases, bases, btb, C / 8, 8, R, R, R, sCR, sCR, sRR,
            nullptr, nullptr, 0L, nullptr, nullptr);
        // coef = coef * xtb / (coef @ btb + eps)
        mu_update_kernel<<<dim3(N / 4, B), blk, 0, stream>>>(coef, xtb, btb, N);
        // xc = X @ coef  (split-K=8, atomic)
        hipMemsetAsync(xc, 0, (size_t)B * C * R * sizeof(float), stream);
        gemm_kernel<0, 0, 1><<<dim3(1, C / BM, B * 8), blk, 0, stream>>>(
            Xb, coef, xc, N / 8, 8, N, R, R, sCN, sNR, sCR,
            nullptr, nullptr, 0L, nullptr, nullptr);
        // ctc = coef^T @ coef  (split-K=32, atomic)
        hipMemsetAsync(ctc, 0, (size_t)B * R * R * sizeof(float), stream);
        gemm_kernel<1, 0, 1><<<dim3(1, 1, B * 32), blk, 0, stream>>>(
            coef, coef, ctc, N / 32, 32, R, R, R, sNR, sNR, sRR,
            nullptr, nullptr, 0L, nullptr, nullptr);
        // bases = bases * xc / (bases @ ctc + eps)
        mu_update_kernel<<<dim3(C / 4, B), blk, 0, stream>>>(bases, xc, ctc, C);
    }

    // final differentiable coef refinement
    gemm_kernel<1, 0, 0><<<dim3(R / BN, N / BM, B), blk, 0, stream>>>(
        Xb, bases, xtb, C, 1, N, R, R, sCN, sCR, sNR,
        nullptr, nullptr, 0L, nullptr, nullptr);
    hipMemsetAsync(btb, 0, (size_t)B * R * R * sizeof(float), stream);
    gemm_kernel<1, 0, 1><<<dim3(1, 1, B * 8), blk, 0, stream>>>(
        bases, bases, btb, C / 8, 8, R, R, R, sCR, sCR, sRR,
        nullptr, nullptr, 0L, nullptr, nullptr);
    mu_update_kernel<<<dim3(N / 4, B), blk, 0, stream>>>(coef, xtb, btb, N);

    // Zb = bases @ coef^T
    gemm_kernel<0, 1, 0><<<dim3(N / BN, C / BM, B), blk, 0, stream>>>(
        bases, coef, Zb, R, 1, R, R, N, sCR, sNR, sCN,
        nullptr, nullptr, 0L, nullptr, nullptr);

    // Xb = relu(w_cheese @ Zb + b_cheese)   (Xb no longer needed as NMF input)
    gemm_kernel<0, 0, 2><<<dim3(N / BN, C / BM, B), blk, 0, stream>>>(
        w_cheese, Zb, Xb, C, 1, C, N, N, 0L, sCN, sCN,
        b_cheese, nullptr, 0L, nullptr, nullptr);

    // out = relu(coef_ham * (w_upper @ Xb) + coef_shortcut * x)
    gemm_kernel<0, 0, 3><<<dim3(N / BN, C / BM, B), blk, 0, stream>>>(
        w_upper, Xb, out, C, 1, C, N, N, 0L, sCN, sCN,
        nullptr, x_in, sCN, cham, csc);
}

// Round 3
// 1448.590 us; speedup vs baseline: 1.5311x; 1.3841x over previous
//
#include <hip/hip_runtime.h>

#define NMF_EPS 1e-6f

typedef unsigned short ushort_t;
typedef __attribute__((ext_vector_type(8))) short bf16x8;
typedef __attribute__((ext_vector_type(4))) float f32x4;

// ---------- bf16 helpers (RNE) ----------
__device__ __forceinline__ ushort_t f2bf(float f) {
    unsigned int u = __float_as_uint(f);
    return (ushort_t)((u + 0x7FFFu + ((u >> 16) & 1u)) >> 16);
}
__device__ __forceinline__ float bf2f(ushort_t h) {
    return __uint_as_float(((unsigned int)h) << 16);
}

// async global->LDS, 16B per lane; LDS dest = wave-uniform base + lane*16
__device__ __forceinline__ void gl_lds16(const ushort_t* g, ushort_t* l) {
    __builtin_amdgcn_global_load_lds(
        (const __attribute__((address_space(1))) unsigned int*)g,
        (__attribute__((address_space(3))) unsigned int*)l,
        16, 0, 0);
}

// =====================================================================
// MFMA GEMM: C[m,n] = op( sum_k A[m,k] * B[n,k] )
// A: bf16 [M,K] row-major (hi, + lo if SPLIT), unbatched (weights)
// B: bf16 [N,K] row-major k-fastest per batch (hi, + lo if SPLIT)
// SPLIT=1: acc = ah*bh + ah*bl + al*bh  (fp32-accurate)
// EPI 2: C = relu(acc + bias[m])            -> fp32 [M,N]
// EPI 3: C = relu(ham*acc + sc*res[m,n])    -> fp32 [M,N]
// tile 128x128, BK=32, 256 threads (4 waves, 2x2 of 64x64), 16x16x32 bf16
// =====================================================================
template<int SPLIT, int EPI>
__global__ __launch_bounds__(256) void mfma_gemm(
    const ushort_t* __restrict__ Ah, const ushort_t* __restrict__ Al,
    const ushort_t* __restrict__ Bh, const ushort_t* __restrict__ Bl,
    float* __restrict__ C, int M, int N, int K,
    long sB, long sC,
    const float* __restrict__ bias,
    const float* __restrict__ res, long sRes,
    const float* __restrict__ hamp, const float* __restrict__ scp)
{
    __shared__ ushort_t sAh[128 * 32];
    __shared__ ushort_t sBh[128 * 32];
    __shared__ ushort_t sAl[SPLIT ? 128 * 32 : 8];
    __shared__ ushort_t sBl[SPLIT ? 128 * 32 : 8];

    const int tid  = threadIdx.x;
    const int wave = tid >> 6, lane = tid & 63;
    const int quad = lane >> 4, lr = lane & 15;
    const int batch = blockIdx.z;
    const int m0 = blockIdx.y * 128, n0 = blockIdx.x * 128;

    const ushort_t* Bhb = Bh + (long)batch * sB;
    const ushort_t* Blb = SPLIT ? (Bl + (long)batch * sB) : nullptr;

    f32x4 acc[4][4];
    #pragma unroll
    for (int i = 0; i < 4; ++i)
        #pragma unroll
        for (int j = 0; j < 4; ++j)
            acc[i][j] = (f32x4){0.f, 0.f, 0.f, 0.f};

    // staging assignment: 8 x 1KB instructions per 8KB tile buffer; wave issues 2
    const int q   = wave * 2;
    const int ra0 = (q + 0) * 16 + (lane >> 2);
    const int ra1 = (q + 1) * 16 + (lane >> 2);
    const int ko  = (lane & 3) * 8;

    const int wm = (wave & 1) * 64, wn = (wave >> 1) * 64;

    for (int k0 = 0; k0 < K; k0 += 32) {
        gl_lds16(&Ah [(long)(m0 + ra0) * K + k0 + ko], &sAh[(q + 0) * 512]);
        gl_lds16(&Ah [(long)(m0 + ra1) * K + k0 + ko], &sAh[(q + 1) * 512]);
        gl_lds16(&Bhb[(long)(n0 + ra0) * K + k0 + ko], &sBh[(q + 0) * 512]);
        gl_lds16(&Bhb[(long)(n0 + ra1) * K + k0 + ko], &sBh[(q + 1) * 512]);
        if constexpr (SPLIT) {
            gl_lds16(&Al [(long)(m0 + ra0) * K + k0 + ko], &sAl[(q + 0) * 512]);
            gl_lds16(&Al [(long)(m0 + ra1) * K + k0 + ko], &sAl[(q + 1) * 512]);
            gl_lds16(&Blb[(long)(n0 + ra0) * K + k0 + ko], &sBl[(q + 0) * 512]);
            gl_lds16(&Blb[(long)(n0 + ra1) * K + k0 + ko], &sBl[(q + 1) * 512]);
        }
        __syncthreads();

        bf16x8 af[4], bfr[4], afl[4], bfl[4];
        #pragma unroll
        for (int i = 0; i < 4; ++i)
            af[i] = *(const bf16x8*)&sAh[(wm + i * 16 + lr) * 32 + quad * 8];
        #pragma unroll
        for (int j = 0; j < 4; ++j)
            bfr[j] = *(const bf16x8*)&sBh[(wn + j * 16 + lr) * 32 + quad * 8];
        if constexpr (SPLIT) {
            #pragma unroll
            for (int i = 0; i < 4; ++i)
                afl[i] = *(const bf16x8*)&sAl[(wm + i * 16 + lr) * 32 + quad * 8];
            #pragma unroll
            for (int j = 0; j < 4; ++j)
                bfl[j] = *(const bf16x8*)&sBl[(wn + j * 16 + lr) * 32 + quad * 8];
        }

        #pragma unroll
        for (int i = 0; i < 4; ++i)
            #pragma unroll
            for (int j = 0; j < 4; ++j) {
                acc[i][j] = __builtin_amdgcn_mfma_f32_16x16x32_bf16(af[i], bfr[j], acc[i][j], 0, 0, 0);
                if constexpr (SPLIT) {
                    acc[i][j] = __builtin_amdgcn_mfma_f32_16x16x32_bf16(af[i], bfl[j], acc[i][j], 0, 0, 0);
                    acc[i][j] = __builtin_amdgcn_mfma_f32_16x16x32_bf16(afl[i], bfr[j], acc[i][j], 0, 0, 0);
                }
            }
        __syncthreads();
    }

    // epilogue: row = m0+wm+i*16+quad*4+r, col = n0+wn+j*16+lr
    float hm = 1.f, sc = 0.f;
    if (EPI == 3) { hm = *hamp; sc = *scp; }
    float* Cb = C + (long)batch * sC;
    #pragma unroll
    for (int i = 0; i < 4; ++i) {
        #pragma unroll
        for (int j = 0; j < 4; ++j) {
            const int mbase = m0 + wm + i * 16 + quad * 4;
            const int n     = n0 + wn + j * 16 + lr;
            #pragma unroll
            for (int r = 0; r < 4; ++r) {
                float v = acc[i][j][r];
                if (EPI == 2) v = fmaxf(v + bias[mbase + r], 0.f);
                if (EPI == 3) {
                    float rv = res[(long)batch * sRes + (long)(mbase + r) * N + n];
                    v = fmaxf(fmaf(hm, v, sc * rv), 0.f);
                }
                Cb[(long)(mbase + r) * N + n] = v;
            }
        }
    }
}

// =====================================================================
// fp32 tiled GEMM (unchanged core), EPI:
//  0 plain fp32 store; 1 atomicAdd; 2 relu(acc+bias) fp32;
//  4 relu(acc+bias) -> bf16 TRANSPOSED store  C_t[n, m] (C is ushort*, ldc = M-stride)
// =====================================================================
constexpr int BM = 64, BN = 64, BK = 16;

template<int ALAY, int BLAY, int EPI>
__global__ __launch_bounds__(256) void gemm_kernel(
    const float* __restrict__ A, const float* __restrict__ B, float* __restrict__ C,
    int Kchunk, int kchunks,
    int lda, int ldb, int ldc,
    long sA, long sB, long sC,
    const float* __restrict__ bias)
{
    __shared__ float As[BK][BM + 4];
    __shared__ float Bs[BK][BN + 4];

    const int bz    = blockIdx.z;
    const int batch = bz / kchunks;
    const int kc    = bz - batch * kchunks;
    const int k0    = kc * Kchunk;

    const float* Ab = A + (long)batch * sA;
    const float* Bb = B + (long)batch * sB;

    const int m0  = blockIdx.y * BM;
    const int n0  = blockIdx.x * BN;
    const int tid = threadIdx.x;
    const int ty  = tid >> 4, tx = tid & 15;

    float acc[4][4] = {};

    for (int kt = 0; kt < Kchunk; kt += BK) {
        if (ALAY == 0) {
            const int m = tid >> 2, k4 = (tid & 3) << 2;
            float4 v = *(const float4*)&Ab[(long)(m0 + m) * lda + (k0 + kt + k4)];
            As[k4 + 0][m] = v.x; As[k4 + 1][m] = v.y;
            As[k4 + 2][m] = v.z; As[k4 + 3][m] = v.w;
        } else {
            const int k = tid >> 4, m4 = (tid & 15) << 2;
            float4 v = *(const float4*)&Ab[(long)(k0 + kt + k) * lda + (m0 + m4)];
            *(float4*)&As[k][m4] = v;
        }
        if (BLAY == 0) {
            const int k = tid >> 4, n4 = (tid & 15) << 2;
            float4 v = *(const float4*)&Bb[(long)(k0 + kt + k) * ldb + (n0 + n4)];
            *(float4*)&Bs[k][n4] = v;
        } else {
            const int n = tid >> 2, k4 = (tid & 3) << 2;
            float4 v = *(const float4*)&Bb[(long)(n0 + n) * ldb + (k0 + kt + k4)];
            Bs[k4 + 0][n] = v.x; Bs[k4 + 1][n] = v.y;
            Bs[k4 + 2][n] = v.z; Bs[k4 + 3][n] = v.w;
        }
        __syncthreads();
        #pragma unroll
        for (int k = 0; k < BK; ++k) {
            float4 a4 = *(const float4*)&As[k][ty << 2];
            float4 b4 = *(const float4*)&Bs[k][tx << 2];
            float av[4] = {a4.x, a4.y, a4.z, a4.w};
            float bv[4] = {b4.x, b4.y, b4.z, b4.w};
            #pragma unroll
            for (int i = 0; i < 4; ++i)
                #pragma unroll
                for (int j = 0; j < 4; ++j)
                    acc[i][j] = fmaf(av[i], bv[j], acc[i][j]);
        }
        __syncthreads();
    }

    const int mb = m0 + (ty << 2), nb = n0 + (tx << 2);
    if (EPI == 1) {
        float* Cb = C + (long)batch * sC;
        #pragma unroll
        for (int i = 0; i < 4; ++i)
            #pragma unroll
            for (int j = 0; j < 4; ++j)
                atomicAdd(&Cb[(long)(mb + i) * ldc + nb + j], acc[i][j]);
    } else if (EPI == 4) {
        ushort_t* Cu = (ushort_t*)C + (long)batch * sC;
        #pragma unroll
        for (int j = 0; j < 4; ++j) {
            ushort_t pk[4];
            #pragma unroll
            for (int i = 0; i < 4; ++i)
                pk[i] = f2bf(fmaxf(acc[i][j] + bias[mb + i], 0.f));
            *(ushort4*)&Cu[(long)(nb + j) * ldc + mb] =
                make_ushort4(pk[0], pk[1], pk[2], pk[3]);
        }
    } else {
        float* Cb = C + (long)batch * sC;
        #pragma unroll
        for (int i = 0; i < 4; ++i) {
            float4 o = make_float4(acc[i][0], acc[i][1], acc[i][2], acc[i][3]);
            if (EPI == 2) {
                float bvv = bias[mb + i];
                o.x = fmaxf(o.x + bvv, 0.f); o.y = fmaxf(o.y + bvv, 0.f);
                o.z = fmaxf(o.z + bvv, 0.f); o.w = fmaxf(o.w + bvv, 0.f);
            }
            *(float4*)&Cb[(long)(mb + i) * ldc + nb] = o;
        }
    }
}

// ---------- casts ----------
// x [b][c][n] fp32 -> xt hi/lo [b][n][c] bf16 (64x64 LDS transpose tiles)
__global__ __launch_bounds__(256) void cast_x_t(const float* __restrict__ x,
                                                ushort_t* __restrict__ hi,
                                                ushort_t* __restrict__ lo)
{
    __shared__ float t[64][65];
    const int b = blockIdx.z, c0 = blockIdx.y * 64, n0 = blockIdx.x * 64;
    const int tid = threadIdx.x, tx = tid & 63, ty = tid >> 6;
    const float* xb = x + (long)b * 512 * 4096;
    #pragma unroll 4
    for (int s = ty; s < 64; s += 4)
        t[s][tx] = xb[(long)(c0 + s) * 4096 + n0 + tx];
    __syncthreads();
    #pragma unroll 4
    for (int s = ty; s < 64; s += 4) {
        float v = t[tx][s];                 // n = n0+s, c = c0+tx
        long idx = (long)b * 4096 * 512 + (long)(n0 + s) * 512 + c0 + tx;
        ushort_t h = f2bf(v);
        hi[idx] = h;
        lo[idx] = f2bf(v - bf2f(h));
    }
}

__global__ void cast_w_split(const float* __restrict__ w, ushort_t* __restrict__ hi,
                             ushort_t* __restrict__ lo, int n)
{
    int i = blockIdx.x * 256 + threadIdx.x;
    if (i < n) {
        float v = w[i];
        ushort_t h = f2bf(v);
        hi[i] = h;
        lo[i] = f2bf(v - bf2f(h));
    }
}

__global__ void cast_w_plain(const float* __restrict__ w, ushort_t* __restrict__ o, int n)
{
    int i = blockIdx.x * 256 + threadIdx.x;
    if (i < n) o[i] = f2bf(w[i]);
}

// ---------- small fp32 kernels (unchanged) ----------
__global__ __launch_bounds__(1024) void l2norm_kernel(const float* __restrict__ b0,
                                                      float* __restrict__ bases)
{
    __shared__ float part[16][64];
    const int b = blockIdx.x;
    const int tid = threadIdx.x;
    const int r = tid & 63, slice = tid >> 6;
    const float* src = b0 + (long)b * 512 * 64;
    float* dst = bases + (long)b * 512 * 64;
    float s = 0.f;
    #pragma unroll 4
    for (int d = slice; d < 512; d += 16) {
        float v = src[d * 64 + r];
        s = fmaf(v, v, s);
    }
    part[slice][r] = s;
    __syncthreads();
    if (slice == 0) {
        float t = 0.f;
        #pragma unroll
        for (int i = 0; i < 16; ++i) t += part[i][r];
        part[0][r] = 1.0f / fmaxf(sqrtf(t), 1e-12f);
    }
    __syncthreads();
    const float inv = part[0][r];
    #pragma unroll 4
    for (int d = slice; d < 512; d += 16)
        dst[d * 64 + r] = src[d * 64 + r] * inv;
}

__global__ __launch_bounds__(256) void softmax_kernel(const float* __restrict__ xtb,
                                                      float* __restrict__ coef)
{
    const long row = (long)blockIdx.x * 4 + (threadIdx.x >> 6);
    const int lane = threadIdx.x & 63;
    float v = xtb[row * 64 + lane];
    float m = v;
    #pragma unroll
    for (int off = 32; off; off >>= 1) m = fmaxf(m, __shfl_xor(m, off, 64));
    float e = __expf(v - m);
    float s = e;
    #pragma unroll
    for (int off = 32; off; off >>= 1) s += __shfl_xor(s, off, 64);
    coef[row * 64 + lane] = e / s;
}

__global__ __launch_bounds__(256) void mu_update_kernel(
    float* __restrict__ T, const float* __restrict__ Num, const float* __restrict__ G,
    int rows_per_batch)
{
    __shared__ float Gl[64 * 64];
    const int b   = blockIdx.y;
    const int tid = threadIdx.x;
    const float* Gb = G + (long)b * 4096;
    for (int i = tid; i < 4096; i += 256) Gl[i] = Gb[i];
    __syncthreads();
    const int wave = tid >> 6, lane = tid & 63;
    const long row = (long)b * rows_per_batch + (long)blockIdx.x * 4 + wave;
    const float c = T[row * 64 + lane];
    const float t = Num[row * 64 + lane];
    float denom = 0.f;
    #pragma unroll 8
    for (int s = 0; s < 64; ++s) {
        float cs = __shfl(c, s, 64);
        denom = fmaf(cs, Gl[s * 64 + lane], denom);
    }
    T[row * 64 + lane] = c * t / (denom + NMF_EPS);
}

extern "C" void kernel_launch(void* const* d_in, const int* in_sizes, int n_in,
                              void* d_out, int out_size, void* d_ws, size_t ws_size,
                              hipStream_t stream)
{
    const float* x_in     = (const float*)d_in[0]; // [8,512,64,64]
    const float* bases0   = (const float*)d_in[1]; // [8,512,64]
    const float* w_lower  = (const float*)d_in[2]; // [512,512]
    const float* b_lower  = (const float*)d_in[3];
    const float* w_cheese = (const float*)d_in[4];
    const float* b_cheese = (const float*)d_in[5];
    const float* w_upper  = (const float*)d_in[6];
    const float* csc      = (const float*)d_in[7];
    const float* cham     = (const float*)d_in[8];
    float* out = (float*)d_out;

    const int B = 8, C = 512, N = 4096, R = 64;
    const long sCN = (long)C * N, sNR = (long)N * R, sCR = (long)C * R, sRR = (long)R * R;
    const long sNC_u = (long)N * C;  // bf16 activation batch stride (elements)

    // ---- workspace layout (floats): total ~38.34M f = 153 MB (same as prior rounds)
    float* ws = (float*)d_ws;
    float*    Xb    = ws;                              // 16,777,216 f  [B,C,N] fp32 NMF x
    ushort_t* xt_hi = (ushort_t*)(Xb + 16777216);      // 16,777,216 u  [B,N,C] bf16 hi
    ushort_t* xt_lo = xt_hi + 16777216;                // 16,777,216 u  lo
    float*    coef  = (float*)(xt_lo + 16777216);      // 2,097,152 f
    float*    xtb   = coef + 2097152;                  // 2,097,152 f
    float*    bases = xtb + 2097152;                   //   262,144 f
    float*    btb   = bases + 262144;                  //    32,768 f
    float*    ctc   = btb + 32768;                     //    32,768 f
    float*    xc    = ctc + 32768;                     //   262,144 f

    // aliases into regions that are dead at time of use:
    ushort_t* wl_hi    = (ushort_t*)xc;                // xc untouched until NMF loop
    ushort_t* wl_lo    = wl_hi + 262144;
    ushort_t* cheese_t = xt_hi;                        // xt dead after lower GEMM
    float*    WcB      = (float*)xt_lo;                // [B,512,64] fp32
    ushort_t* w_up     = (ushort_t*)((float*)xt_lo + 262144);

    const dim3 blk(256);

    // bases = l2norm(bases0)
    l2norm_kernel<<<dim3(B), dim3(1024), 0, stream>>>(bases0, bases);

    // casts for lower MFMA
    cast_w_split<<<dim3(1024), blk, 0, stream>>>(w_lower, wl_hi, wl_lo, C * C);
    cast_x_t<<<dim3(N / 64, C / 64, B), blk, 0, stream>>>(x_in, xt_hi, xt_lo);

    // Xb = relu(w_lower @ x + b_lower)   [split-bf16 MFMA, fp32-accurate]
    mfma_gemm<1, 2><<<dim3(N / 128, C / 128, B), blk, 0, stream>>>(
        wl_hi, wl_lo, xt_hi, xt_lo, Xb, C, N, C, sNC_u, sCN,
        b_lower, nullptr, 0L, nullptr, nullptr);

    // xtb = X^T @ bases ; coef = softmax_r(xtb)
    gemm_kernel<1, 0, 0><<<dim3(R / BN, N / BM, B), blk, 0, stream>>>(
        Xb, bases, xtb, C, 1, N, R, R, sCN, sCR, sNR, nullptr);
    softmax_kernel<<<dim3(B * N / 4), blk, 0, stream>>>(xtb, coef);

    for (int step = 0; step < 6; ++step) {
        gemm_kernel<1, 0, 0><<<dim3(R / BN, N / BM, B), blk, 0, stream>>>(
            Xb, bases, xtb, C, 1, N, R, R, sCN, sCR, sNR, nullptr);
        hipMemsetAsync(btb, 0, (size_t)B * R * R * sizeof(float), stream);
        gemm_kernel<1, 0, 1><<<dim3(1, 1, B * 8), blk, 0, stream>>>(
            bases, bases, btb, C / 8, 8, R, R, R, sCR, sCR, sRR, nullptr);
        mu_update_kernel<<<dim3(N / 4, B), blk, 0, stream>>>(coef, xtb, btb, N);
        hipMemsetAsync(xc, 0, (size_t)B * C * R * sizeof(float), stream);
        gemm_kernel<0, 0, 1><<<dim3(1, C / BM, B * 8), blk, 0, stream>>>(
            Xb, coef, xc, N / 8, 8, N, R, R, sCN, sNR, sCR, nullptr);
        hipMemsetAsync(ctc, 0, (size_t)B * R * R * sizeof(float), stream);
        gemm_kernel<1, 0, 1><<<dim3(1, 1, B * 32), blk, 0, stream>>>(
            coef, coef, ctc, N / 32, 32, R, R, R, sNR, sNR, sRR, nullptr);
        mu_update_kernel<<<dim3(C / 4, B), blk, 0, stream>>>(bases, xc, ctc, C);
    }

    // final differentiable coef refinement
    gemm_kernel<1, 0, 0><<<dim3(R / BN, N / BM, B), blk, 0, stream>>>(
        Xb, bases, xtb, C, 1, N, R, R, sCN, sCR, sNR, nullptr);
    hipMemsetAsync(btb, 0, (size_t)B * R * R * sizeof(float), stream);
    gemm_kernel<1, 0, 1><<<dim3(1, 1, B * 8), blk, 0, stream>>>(
        bases, bases, btb, C / 8, 8, R, R, R, sCR, sCR, sRR, nullptr);
    mu_update_kernel<<<dim3(N / 4, B), blk, 0, stream>>>(coef, xtb, btb, N);

    // cheese via associativity: WcB = w_cheese @ bases  [512,64] per batch
    gemm_kernel<0, 0, 0><<<dim3(1, C / BM, B), blk, 0, stream>>>(
        w_cheese, bases, WcB, C, 1, C, R, R, 0L, sCR, sCR, nullptr);
    cast_w_plain<<<dim3(1024), blk, 0, stream>>>(w_upper, w_up, C * C);

    // cheese_t[n][m] = bf16(relu(WcB @ coef^T + b_cheese))   (K = 64)
    gemm_kernel<0, 1, 4><<<dim3(N / BN, C / BM, B), blk, 0, stream>>>(
        WcB, coef, (float*)cheese_t, R, 1, R, R, C, sCR, sNR, sNC_u, b_cheese);

    // out = relu(ham * (w_upper @ cheese) + sc * x)   [plain bf16 MFMA]
    mfma_gemm<0, 3><<<dim3(N / 128, C / 128, B), blk, 0, stream>>>(
        w_up, nullptr, cheese_t, nullptr, out, C, N, C, sNC_u, sCN,
        nullptr, x_in, sCN, cham, csc);
}

// Round 4
// 1225.659 us; speedup vs baseline: 1.8096x; 1.1819x over previous
//
#include <hip/hip_runtime.h>

#define NMF_EPS 1e-6f

typedef unsigned short ushort_t;
typedef __attribute__((ext_vector_type(8))) short bf16x8;
typedef __attribute__((ext_vector_type(4))) float f32x4;

// ---------- bf16 helpers (RNE) ----------
__device__ __forceinline__ ushort_t f2bf(float f) {
    unsigned int u = __float_as_uint(f);
    return (ushort_t)((u + 0x7FFFu + ((u >> 16) & 1u)) >> 16);
}
__device__ __forceinline__ float bf2f(ushort_t h) {
    return __uint_as_float(((unsigned int)h) << 16);
}

// async global->LDS, 16B per lane; LDS dest = wave-uniform base + lane*16
__device__ __forceinline__ void gl_lds16(const ushort_t* g, ushort_t* l) {
    __builtin_amdgcn_global_load_lds(
        (const __attribute__((address_space(1))) unsigned int*)g,
        (__attribute__((address_space(3))) unsigned int*)l,
        16, 0, 0);
}

// =====================================================================
// Big MFMA GEMM: C[m,n] = op( sum_k A[m,k] * B[n,k] )
// A: bf16 [M,K] (hi, + lo if SPLIT), unbatched weights
// B: bf16 [N,K] k-fastest per batch (hi, + lo if SPLIT)
// EPI 2: relu(acc+bias[m]) -> bf16 hi/lo, TRANSPOSED nd layout [n][M]
// EPI 3: relu(ham*acc + sc*res[m,n]) -> fp32 [M,N]
// tile 128x128, BK=32, 256 threads (2x2 waves of 64x64), 16x16x32 bf16
// =====================================================================
template<int SPLIT, int EPI>
__global__ __launch_bounds__(256) void mfma_gemm(
    const ushort_t* __restrict__ Ah, const ushort_t* __restrict__ Al,
    const ushort_t* __restrict__ Bh, const ushort_t* __restrict__ Bl,
    float* __restrict__ C, ushort_t* __restrict__ Chi, ushort_t* __restrict__ Clo,
    int M, int N, int K,
    long sB, long sC,
    const float* __restrict__ bias,
    const float* __restrict__ res, long sRes,
    const float* __restrict__ hamp, const float* __restrict__ scp)
{
    __shared__ ushort_t sAh[128 * 32];
    __shared__ ushort_t sBh[128 * 32];
    __shared__ ushort_t sAl[SPLIT ? 128 * 32 : 8];
    __shared__ ushort_t sBl[SPLIT ? 128 * 32 : 8];

    const int tid  = threadIdx.x;
    const int wave = tid >> 6, lane = tid & 63;
    const int quad = lane >> 4, lr = lane & 15;
    const int batch = blockIdx.z;
    const int m0 = blockIdx.y * 128, n0 = blockIdx.x * 128;

    const ushort_t* Bhb = Bh + (long)batch * sB;
    const ushort_t* Blb = SPLIT ? (Bl + (long)batch * sB) : nullptr;

    f32x4 acc[4][4];
    #pragma unroll
    for (int i = 0; i < 4; ++i)
        #pragma unroll
        for (int j = 0; j < 4; ++j)
            acc[i][j] = (f32x4){0.f, 0.f, 0.f, 0.f};

    const int q   = wave * 2;
    const int ra0 = (q + 0) * 16 + (lane >> 2);
    const int ra1 = (q + 1) * 16 + (lane >> 2);
    const int ko  = (lane & 3) * 8;
    const int wm = (wave & 1) * 64, wn = (wave >> 1) * 64;

    for (int k0 = 0; k0 < K; k0 += 32) {
        gl_lds16(&Ah [(long)(m0 + ra0) * K + k0 + ko], &sAh[(q + 0) * 512]);
        gl_lds16(&Ah [(long)(m0 + ra1) * K + k0 + ko], &sAh[(q + 1) * 512]);
        gl_lds16(&Bhb[(long)(n0 + ra0) * K + k0 + ko], &sBh[(q + 0) * 512]);
        gl_lds16(&Bhb[(long)(n0 + ra1) * K + k0 + ko], &sBh[(q + 1) * 512]);
        if constexpr (SPLIT) {
            gl_lds16(&Al [(long)(m0 + ra0) * K + k0 + ko], &sAl[(q + 0) * 512]);
            gl_lds16(&Al [(long)(m0 + ra1) * K + k0 + ko], &sAl[(q + 1) * 512]);
            gl_lds16(&Blb[(long)(n0 + ra0) * K + k0 + ko], &sBl[(q + 0) * 512]);
            gl_lds16(&Blb[(long)(n0 + ra1) * K + k0 + ko], &sBl[(q + 1) * 512]);
        }
        __syncthreads();

        bf16x8 af[4], bfr[4], afl[4], bfl[4];
        #pragma unroll
        for (int i = 0; i < 4; ++i)
            af[i] = *(const bf16x8*)&sAh[(wm + i * 16 + lr) * 32 + quad * 8];
        #pragma unroll
        for (int j = 0; j < 4; ++j)
            bfr[j] = *(const bf16x8*)&sBh[(wn + j * 16 + lr) * 32 + quad * 8];
        if constexpr (SPLIT) {
            #pragma unroll
            for (int i = 0; i < 4; ++i)
                afl[i] = *(const bf16x8*)&sAl[(wm + i * 16 + lr) * 32 + quad * 8];
            #pragma unroll
            for (int j = 0; j < 4; ++j)
                bfl[j] = *(const bf16x8*)&sBl[(wn + j * 16 + lr) * 32 + quad * 8];
        }

        #pragma unroll
        for (int i = 0; i < 4; ++i)
            #pragma unroll
            for (int j = 0; j < 4; ++j) {
                acc[i][j] = __builtin_amdgcn_mfma_f32_16x16x32_bf16(af[i], bfr[j], acc[i][j], 0, 0, 0);
                if constexpr (SPLIT) {
                    acc[i][j] = __builtin_amdgcn_mfma_f32_16x16x32_bf16(af[i], bfl[j], acc[i][j], 0, 0, 0);
                    acc[i][j] = __builtin_amdgcn_mfma_f32_16x16x32_bf16(afl[i], bfr[j], acc[i][j], 0, 0, 0);
                }
            }
        __syncthreads();
    }

    if (EPI == 2) {
        // relu(acc+bias) -> bf16 hi/lo at [n][M] (m fastest), 8B stores
        ushort_t* Hh = Chi + (long)batch * sC;
        ushort_t* Hl = Clo + (long)batch * sC;
        #pragma unroll
        for (int i = 0; i < 4; ++i) {
            #pragma unroll
            for (int j = 0; j < 4; ++j) {
                const int mbase = m0 + wm + i * 16 + quad * 4;
                const int n     = n0 + wn + j * 16 + lr;
                ushort_t ph[4], pl[4];
                #pragma unroll
                for (int r = 0; r < 4; ++r) {
                    float v = fmaxf(acc[i][j][r] + bias[mbase + r], 0.f);
                    ushort_t h = f2bf(v);
                    ph[r] = h;
                    pl[r] = f2bf(v - bf2f(h));
                }
                *(ushort4*)&Hh[(long)n * M + mbase] = make_ushort4(ph[0], ph[1], ph[2], ph[3]);
                *(ushort4*)&Hl[(long)n * M + mbase] = make_ushort4(pl[0], pl[1], pl[2], pl[3]);
            }
        }
    } else {
        const float hm = *hamp, sc = *scp;
        float* Cb = C + (long)batch * sC;
        #pragma unroll
        for (int i = 0; i < 4; ++i) {
            #pragma unroll
            for (int j = 0; j < 4; ++j) {
                const int mbase = m0 + wm + i * 16 + quad * 4;
                const int n     = n0 + wn + j * 16 + lr;
                #pragma unroll
                for (int r = 0; r < 4; ++r) {
                    float rv = res[(long)batch * sRes + (long)(mbase + r) * N + n];
                    Cb[(long)(mbase + r) * N + n] = fmaxf(fmaf(hm, acc[i][j][r], sc * rv), 0.f);
                }
            }
        }
    }
}

// =====================================================================
// Skinny MFMA GEMM: C[m, r] (+)= sum_k A[m,k]*B[r,k], Rout = 64
// A: bf16 hi/lo batched [.., ldA] k-fastest; B: bf16 hi/lo batched [64, ldB]
// tile 64(M) x 64(R) x BK32; wave w owns rows 16w..16w+16; split 3-MFMA.
// grid = (kchunks, M/64, batches); ATOMIC=1 -> atomicAdd (C pre-zeroed)
// =====================================================================
template<int ATOMIC>
__global__ __launch_bounds__(256) void mfma_skinny(
    const ushort_t* __restrict__ Ah, const ushort_t* __restrict__ Al,
    const ushort_t* __restrict__ Bh, const ushort_t* __restrict__ Bl,
    float* __restrict__ C,
    int ldA, int ldB, int Kchunk,
    long sA, long sB, long sC)
{
    __shared__ ushort_t sAh[64 * 32], sAl[64 * 32], sBh[64 * 32], sBl[64 * 32];
    const int tid = threadIdx.x, wave = tid >> 6, lane = tid & 63;
    const int quad = lane >> 4, lr = lane & 15;
    const int batch = blockIdx.z;
    const int m0 = blockIdx.y * 64;
    const int k0 = blockIdx.x * Kchunk;

    const ushort_t* Ab  = Ah + (long)batch * sA;
    const ushort_t* Alb = Al + (long)batch * sA;
    const ushort_t* Bb  = Bh + (long)batch * sB;
    const ushort_t* Blb = Bl + (long)batch * sB;

    const int srow = wave * 16 + (lane >> 2);
    const int koff = (lane & 3) * 8;

    f32x4 acc[4];
    #pragma unroll
    for (int j = 0; j < 4; ++j) acc[j] = (f32x4){0.f, 0.f, 0.f, 0.f};

    for (int kt = 0; kt < Kchunk; kt += 32) {
        gl_lds16(&Ab [(long)(m0 + srow) * ldA + k0 + kt + koff], &sAh[wave * 512]);
        gl_lds16(&Alb[(long)(m0 + srow) * ldA + k0 + kt + koff], &sAl[wave * 512]);
        gl_lds16(&Bb [(long)srow * ldB + k0 + kt + koff], &sBh[wave * 512]);
        gl_lds16(&Blb[(long)srow * ldB + k0 + kt + koff], &sBl[wave * 512]);
        __syncthreads();
        bf16x8 ah = *(const bf16x8*)&sAh[(wave * 16 + lr) * 32 + quad * 8];
        bf16x8 al = *(const bf16x8*)&sAl[(wave * 16 + lr) * 32 + quad * 8];
        #pragma unroll
        for (int j = 0; j < 4; ++j) {
            bf16x8 bh = *(const bf16x8*)&sBh[(j * 16 + lr) * 32 + quad * 8];
            bf16x8 bl = *(const bf16x8*)&sBl[(j * 16 + lr) * 32 + quad * 8];
            acc[j] = __builtin_amdgcn_mfma_f32_16x16x32_bf16(ah, bh, acc[j], 0, 0, 0);
            acc[j] = __builtin_amdgcn_mfma_f32_16x16x32_bf16(ah, bl, acc[j], 0, 0, 0);
            acc[j] = __builtin_amdgcn_mfma_f32_16x16x32_bf16(al, bh, acc[j], 0, 0, 0);
        }
        __syncthreads();
    }

    float* Cb = C + (long)batch * sC;
    #pragma unroll
    for (int j = 0; j < 4; ++j) {
        const int col = j * 16 + lr;
        #pragma unroll
        for (int r = 0; r < 4; ++r) {
            const int m = m0 + wave * 16 + quad * 4 + r;
            if (ATOMIC) atomicAdd(&Cb[(long)m * 64 + col], acc[j][r]);
            else        Cb[(long)m * 64 + col] = acc[j][r];
        }
    }
}

// =====================================================================
// fp32 tiled GEMM (small ops only): EPI 0 plain; 1 atomicAdd;
// 4 relu(acc+bias) -> bf16 TRANSPOSED store C_t[n,m] (C is ushort*, ldc=M-stride)
// =====================================================================
constexpr int BM = 64, BN = 64, BK = 16;

template<int ALAY, int BLAY, int EPI>
__global__ __launch_bounds__(256) void gemm_kernel(
    const float* __restrict__ A, const float* __restrict__ B, float* __restrict__ C,
    int Kchunk, int kchunks,
    int lda, int ldb, int ldc,
    long sA, long sB, long sC,
    const float* __restrict__ bias)
{
    __shared__ float As[BK][BM + 4];
    __shared__ float Bs[BK][BN + 4];

    const int bz    = blockIdx.z;
    const int batch = bz / kchunks;
    const int kc    = bz - batch * kchunks;
    const int k0    = kc * Kchunk;

    const float* Ab = A + (long)batch * sA;
    const float* Bb = B + (long)batch * sB;

    const int m0  = blockIdx.y * BM;
    const int n0  = blockIdx.x * BN;
    const int tid = threadIdx.x;
    const int ty  = tid >> 4, tx = tid & 15;

    float acc[4][4] = {};

    for (int kt = 0; kt < Kchunk; kt += BK) {
        if (ALAY == 0) {
            const int m = tid >> 2, k4 = (tid & 3) << 2;
            float4 v = *(const float4*)&Ab[(long)(m0 + m) * lda + (k0 + kt + k4)];
            As[k4 + 0][m] = v.x; As[k4 + 1][m] = v.y;
            As[k4 + 2][m] = v.z; As[k4 + 3][m] = v.w;
        } else {
            const int k = tid >> 4, m4 = (tid & 15) << 2;
            float4 v = *(const float4*)&Ab[(long)(k0 + kt + k) * lda + (m0 + m4)];
            *(float4*)&As[k][m4] = v;
        }
        if (BLAY == 0) {
            const int k = tid >> 4, n4 = (tid & 15) << 2;
            float4 v = *(const float4*)&Bb[(long)(k0 + kt + k) * ldb + (n0 + n4)];
            *(float4*)&Bs[k][n4] = v;
        } else {
            const int n = tid >> 2, k4 = (tid & 3) << 2;
            float4 v = *(const float4*)&Bb[(long)(n0 + n) * ldb + (k0 + kt + k4)];
            Bs[k4 + 0][n] = v.x; Bs[k4 + 1][n] = v.y;
            Bs[k4 + 2][n] = v.z; Bs[k4 + 3][n] = v.w;
        }
        __syncthreads();
        #pragma unroll
        for (int k = 0; k < BK; ++k) {
            float4 a4 = *(const float4*)&As[k][ty << 2];
            float4 b4 = *(const float4*)&Bs[k][tx << 2];
            float av[4] = {a4.x, a4.y, a4.z, a4.w};
            float bv[4] = {b4.x, b4.y, b4.z, b4.w};
            #pragma unroll
            for (int i = 0; i < 4; ++i)
                #pragma unroll
                for (int j = 0; j < 4; ++j)
                    acc[i][j] = fmaf(av[i], bv[j], acc[i][j]);
        }
        __syncthreads();
    }

    const int mb = m0 + (ty << 2), nb = n0 + (tx << 2);
    if (EPI == 1) {
        float* Cb = C + (long)batch * sC;
        #pragma unroll
        for (int i = 0; i < 4; ++i)
            #pragma unroll
            for (int j = 0; j < 4; ++j)
                atomicAdd(&Cb[(long)(mb + i) * ldc + nb + j], acc[i][j]);
    } else if (EPI == 4) {
        ushort_t* Cu = (ushort_t*)C + (long)batch * sC;
        #pragma unroll
        for (int j = 0; j < 4; ++j) {
            ushort_t pk[4];
            #pragma unroll
            for (int i = 0; i < 4; ++i)
                pk[i] = f2bf(fmaxf(acc[i][j] + bias[mb + i], 0.f));
            *(ushort4*)&Cu[(long)(nb + j) * ldc + mb] =
                make_ushort4(pk[0], pk[1], pk[2], pk[3]);
        }
    } else {
        float* Cb = C + (long)batch * sC;
        #pragma unroll
        for (int i = 0; i < 4; ++i) {
            float4 o = make_float4(acc[i][0], acc[i][1], acc[i][2], acc[i][3]);
            *(float4*)&Cb[(long)(mb + i) * ldc + nb] = o;
        }
    }
}

// ---------- casts / transposes ----------
// x [b][c][n] fp32 -> xt hi/lo [b][n][c] bf16 (input to lower GEMM)
__global__ __launch_bounds__(256) void cast_x_t(const float* __restrict__ x,
                                                ushort_t* __restrict__ hi,
                                                ushort_t* __restrict__ lo)
{
    __shared__ float t[64][65];
    const int b = blockIdx.z, c0 = blockIdx.y * 64, n0 = blockIdx.x * 64;
    const int tid = threadIdx.x, tx = tid & 63, ty = tid >> 6;
    const float* xb = x + (long)b * 512 * 4096;
    #pragma unroll 4
    for (int s = ty; s < 64; s += 4)
        t[s][tx] = xb[(long)(c0 + s) * 4096 + n0 + tx];
    __syncthreads();
    #pragma unroll 4
    for (int s = ty; s < 64; s += 4) {
        float v = t[tx][s];
        long idx = (long)b * 4096 * 512 + (long)(n0 + s) * 512 + c0 + tx;
        ushort_t h = f2bf(v);
        hi[idx] = h;
        lo[idx] = f2bf(v - bf2f(h));
    }
}

// bf16 hi/lo [b][n][c] -> [b][c][n]  (pack hi|lo<<16 through LDS)
__global__ __launch_bounds__(256) void nd2dn(const ushort_t* __restrict__ hi,
                                             const ushort_t* __restrict__ lo,
                                             ushort_t* __restrict__ dhi,
                                             ushort_t* __restrict__ dlo)
{
    __shared__ unsigned int t[64][65];
    const int b = blockIdx.z, n0 = blockIdx.x * 64, c0 = blockIdx.y * 64;
    const int tx = threadIdx.x & 63, ty = threadIdx.x >> 6;
    const long base = (long)b * 2097152;
    #pragma unroll 4
    for (int s = ty; s < 64; s += 4) {
        long idx = base + (long)(n0 + s) * 512 + c0 + tx;
        t[s][tx] = (unsigned)hi[idx] | ((unsigned)lo[idx] << 16);
    }
    __syncthreads();
    #pragma unroll 4
    for (int s = ty; s < 64; s += 4) {
        unsigned v = t[tx][s];
        long idx = base + (long)(c0 + s) * 4096 + n0 + tx;
        dhi[idx] = (ushort_t)(v & 0xffffu);
        dlo[idx] = (ushort_t)(v >> 16);
    }
}

// fp32 [rows, 64] -> bf16 hi/lo [64, rows] per batch (transpose-cast)
__global__ __launch_bounds__(256) void tcast(const float* __restrict__ in,
                                             ushort_t* __restrict__ ohi,
                                             ushort_t* __restrict__ olo,
                                             int rows, long sIn, long sOut)
{
    __shared__ float t[64][65];
    const int b = blockIdx.z, r0 = blockIdx.x * 64;
    const int tx = threadIdx.x & 63, ty = threadIdx.x >> 6;
    const float* ib = in + (long)b * sIn;
    #pragma unroll 4
    for (int s = ty; s < 64; s += 4)
        t[s][tx] = ib[(long)(r0 + s) * 64 + tx];
    __syncthreads();
    #pragma unroll 4
    for (int s = ty; s < 64; s += 4) {
        float v = t[tx][s];
        long idx = (long)b * sOut + (long)s * rows + r0 + tx;
        ushort_t h = f2bf(v);
        ohi[idx] = h;
        olo[idx] = f2bf(v - bf2f(h));
    }
}

__global__ void cast_w_split(const float* __restrict__ w, ushort_t* __restrict__ hi,
                             ushort_t* __restrict__ lo, int n)
{
    int i = blockIdx.x * 256 + threadIdx.x;
    if (i < n) {
        float v = w[i];
        ushort_t h = f2bf(v);
        hi[i] = h;
        lo[i] = f2bf(v - bf2f(h));
    }
}

__global__ void cast_w_plain(const float* __restrict__ w, ushort_t* __restrict__ o, int n)
{
    int i = blockIdx.x * 256 + threadIdx.x;
    if (i < n) o[i] = f2bf(w[i]);
}

// ---------- small fp32 kernels ----------
__global__ __launch_bounds__(1024) void l2norm_kernel(const float* __restrict__ b0,
                                                      float* __restrict__ bases)
{
    __shared__ float part[16][64];
    const int b = blockIdx.x;
    const int tid = threadIdx.x;
    const int r = tid & 63, slice = tid >> 6;
    const float* src = b0 + (long)b * 512 * 64;
    float* dst = bases + (long)b * 512 * 64;
    float s = 0.f;
    #pragma unroll 4
    for (int d = slice; d < 512; d += 16) {
        float v = src[d * 64 + r];
        s = fmaf(v, v, s);
    }
    part[slice][r] = s;
    __syncthreads();
    if (slice == 0) {
        float t = 0.f;
        #pragma unroll
        for (int i = 0; i < 16; ++i) t += part[i][r];
        part[0][r] = 1.0f / fmaxf(sqrtf(t), 1e-12f);
    }
    __syncthreads();
    const float inv = part[0][r];
    #pragma unroll 4
    for (int d = slice; d < 512; d += 16)
        dst[d * 64 + r] = src[d * 64 + r] * inv;
}

__global__ __launch_bounds__(256) void softmax_kernel(const float* __restrict__ xtb,
                                                      float* __restrict__ coef)
{
    const long row = (long)blockIdx.x * 4 + (threadIdx.x >> 6);
    const int lane = threadIdx.x & 63;
    float v = xtb[row * 64 + lane];
    float m = v;
    #pragma unroll
    for (int off = 32; off; off >>= 1) m = fmaxf(m, __shfl_xor(m, off, 64));
    float e = __expf(v - m);
    float s = e;
    #pragma unroll
    for (int off = 32; off; off >>= 1) s += __shfl_xor(s, off, 64);
    coef[row * 64 + lane] = e / s;
}

__global__ __launch_bounds__(256) void mu_update_kernel(
    float* __restrict__ T, const float* __restrict__ Num, const float* __restrict__ G,
    int rows_per_batch)
{
    __shared__ float Gl[64 * 64];
    const int b   = blockIdx.y;
    const int tid = threadIdx.x;
    const float* Gb = G + (long)b * 4096;
    for (int i = tid; i < 4096; i += 256) Gl[i] = Gb[i];
    __syncthreads();
    const int wave = tid >> 6, lane = tid & 63;
    const long row = (long)b * rows_per_batch + (long)blockIdx.x * 4 + wave;
    const float c = T[row * 64 + lane];
    const float t = Num[row * 64 + lane];
    float denom = 0.f;
    #pragma unroll 8
    for (int s = 0; s < 64; ++s) {
        float cs = __shfl(c, s, 64);
        denom = fmaf(cs, Gl[s * 64 + lane], denom);
    }
    T[row * 64 + lane] = c * t / (denom + NMF_EPS);
}

extern "C" void kernel_launch(void* const* d_in, const int* in_sizes, int n_in,
                              void* d_out, int out_size, void* d_ws, size_t ws_size,
                              hipStream_t stream)
{
    const float* x_in     = (const float*)d_in[0]; // [8,512,64,64]
    const float* bases0   = (const float*)d_in[1]; // [8,512,64]
    const float* w_lower  = (const float*)d_in[2];
    const float* b_lower  = (const float*)d_in[3];
    const float* w_cheese = (const float*)d_in[4];
    const float* b_cheese = (const float*)d_in[5];
    const float* w_upper  = (const float*)d_in[6];
    const float* csc      = (const float*)d_in[7];
    const float* cham     = (const float*)d_in[8];
    float* out = (float*)d_out;

    const int B = 8, C = 512, N = 4096, R = 64;
    const long sCN = (long)C * N;      // fp32 [C,N] batch stride
    const long sNC = (long)N * C;      // bf16 nd/dn batch stride (elements)
    const long sNR = (long)N * R, sCR = (long)C * R, sRR = (long)R * R;

    // ---- workspace layout (bytes; total ~132 MB) ----
    char* w = (char*)d_ws;
    ushort_t* X_nd_hi = (ushort_t*)w;            w += 33554432; // [B,N,C]
    ushort_t* xt_hi   = (ushort_t*)w;            w += 33554432; // input x^T; later X_dn_hi
    ushort_t* xt_lo   = (ushort_t*)w;            w += 33554432; // input x^T; later X_dn_lo
    float*    coef    = (float*)w;               w += 8388608;  // [B,N,R]
    float*    xtb     = (float*)w;               w += 8388608;  // [B,N,R]
    ushort_t* ct_hi   = (ushort_t*)w;            w += 4194304;  // coef^T [B,R,N]
    ushort_t* ct_lo   = (ushort_t*)w;            w += 4194304;
    float*    bases   = (float*)w;               w += 1048576;  // [B,C,R]
    float*    xc      = (float*)w;               w += 1048576;  // [B,C,R]
    float*    WcB     = (float*)w;               w += 1048576;  // [B,C,R]
    ushort_t* bt_hi   = (ushort_t*)w;            w += 524288;   // bases^T [B,R,C]
    ushort_t* bt_lo   = (ushort_t*)w;            w += 524288;
    ushort_t* wl_hi   = (ushort_t*)w;            w += 524288;
    ushort_t* wl_lo   = (ushort_t*)w;            w += 524288;
    ushort_t* w_up    = (ushort_t*)w;            w += 524288;
    float*    btb     = (float*)w;               w += 131072;   // [B,R,R]
    float*    ctc     = (float*)w;               w += 131072;   // [B,R,R]

    // aliases (regions dead at time of use):
    ushort_t* X_nd_lo = (ushort_t*)d_out;        // dead before upper GEMM writes out
    ushort_t* X_dn_hi = xt_hi;                   // xt dead after lower GEMM
    ushort_t* X_dn_lo = xt_lo;
    ushort_t* cheese_t = X_nd_hi;                // X_nd dead after final refinement

    const dim3 blk(256);

    // bases = l2norm(bases0); bases_t hi/lo
    l2norm_kernel<<<dim3(B), dim3(1024), 0, stream>>>(bases0, bases);
    tcast<<<dim3(C / 64, 1, B), blk, 0, stream>>>(bases, bt_hi, bt_lo, C, sCR, sCR);

    // weight casts + x transpose-cast
    cast_w_split<<<dim3(1024), blk, 0, stream>>>(w_lower, wl_hi, wl_lo, C * C);
    cast_w_plain<<<dim3(1024), blk, 0, stream>>>(w_upper, w_up, C * C);
    cast_x_t<<<dim3(N / 64, C / 64, B), blk, 0, stream>>>(x_in, xt_hi, xt_lo);

    // X = relu(w_lower @ x + b_lower)  -> bf16 hi/lo nd layout [n][c]
    mfma_gemm<1, 2><<<dim3(N / 128, C / 128, B), blk, 0, stream>>>(
        wl_hi, wl_lo, xt_hi, xt_lo, nullptr, X_nd_hi, X_nd_lo,
        C, N, C, sNC, sNC, b_lower, nullptr, 0L, nullptr, nullptr);

    // X_dn = transpose(X_nd)   (overwrites xt region)
    nd2dn<<<dim3(N / 64, C / 64, B), blk, 0, stream>>>(X_nd_hi, X_nd_lo, X_dn_hi, X_dn_lo);

    // xtb = X^T @ bases; coef = softmax(xtb); coef_t
    mfma_skinny<0><<<dim3(1, N / 64, B), blk, 0, stream>>>(
        X_nd_hi, X_nd_lo, bt_hi, bt_lo, xtb, C, C, C, sNC, sCR, sNR);
    softmax_kernel<<<dim3(B * N / 4), blk, 0, stream>>>(xtb, coef);
    tcast<<<dim3(N / 64, 1, B), blk, 0, stream>>>(coef, ct_hi, ct_lo, N, sNR, sNR);

    for (int step = 0; step < 6; ++step) {
        // xtb = X^T @ bases
        mfma_skinny<0><<<dim3(1, N / 64, B), blk, 0, stream>>>(
            X_nd_hi, X_nd_lo, bt_hi, bt_lo, xtb, C, C, C, sNC, sCR, sNR);
        // btb = bases^T @ bases
        hipMemsetAsync(btb, 0, (size_t)B * R * R * sizeof(float), stream);
        gemm_kernel<1, 0, 1><<<dim3(1, 1, B * 8), blk, 0, stream>>>(
            bases, bases, btb, C / 8, 8, R, R, R, sCR, sCR, sRR, nullptr);
        // coef update + coef_t
        mu_update_kernel<<<dim3(N / 4, B), blk, 0, stream>>>(coef, xtb, btb, N);
        tcast<<<dim3(N / 64, 1, B), blk, 0, stream>>>(coef, ct_hi, ct_lo, N, sNR, sNR);
        // xc = X @ coef   (split-K=8, atomic)
        hipMemsetAsync(xc, 0, (size_t)B * C * R * sizeof(float), stream);
        mfma_skinny<1><<<dim3(8, C / 64, B), blk, 0, stream>>>(
            X_dn_hi, X_dn_lo, ct_hi, ct_lo, xc, N, N, 512, sNC, sNR, sCR);
        // ctc = coef^T @ coef
        hipMemsetAsync(ctc, 0, (size_t)B * R * R * sizeof(float), stream);
        gemm_kernel<1, 0, 1><<<dim3(1, 1, B * 32), blk, 0, stream>>>(
            coef, coef, ctc, N / 32, 32, R, R, R, sNR, sNR, sRR, nullptr);
        // bases update + bases_t
        mu_update_kernel<<<dim3(C / 4, B), blk, 0, stream>>>(bases, xc, ctc, C);
        tcast<<<dim3(C / 64, 1, B), blk, 0, stream>>>(bases, bt_hi, bt_lo, C, sCR, sCR);
    }

    // final differentiable coef refinement
    mfma_skinny<0><<<dim3(1, N / 64, B), blk, 0, stream>>>(
        X_nd_hi, X_nd_lo, bt_hi, bt_lo, xtb, C, C, C, sNC, sCR, sNR);
    hipMemsetAsync(btb, 0, (size_t)B * R * R * sizeof(float), stream);
    gemm_kernel<1, 0, 1><<<dim3(1, 1, B * 8), blk, 0, stream>>>(
        bases, bases, btb, C / 8, 8, R, R, R, sCR, sCR, sRR, nullptr);
    mu_update_kernel<<<dim3(N / 4, B), blk, 0, stream>>>(coef, xtb, btb, N);

    // cheese via associativity: WcB = w_cheese @ bases; cheese_t = bf16(relu(WcB @ coef^T + b))
    gemm_kernel<0, 0, 0><<<dim3(1, C / BM, B), blk, 0, stream>>>(
        w_cheese, bases, WcB, C, 1, C, R, R, 0L, sCR, sCR, nullptr);
    gemm_kernel<0, 1, 4><<<dim3(N / BN, C / BM, B), blk, 0, stream>>>(
        WcB, coef, (float*)cheese_t, R, 1, R, R, C, sCR, sNR, sNC, b_cheese);

    // out = relu(ham * (w_upper @ cheese) + sc * x)
    mfma_gemm<0, 3><<<dim3(N / 128, C / 128, B), blk, 0, stream>>>(
        w_up, nullptr, cheese_t, nullptr, out, nullptr, nullptr,
        C, N, C, sNC, sCN, nullptr, x_in, sCN, cham, csc);
}

// Round 5
// 796.355 us; speedup vs baseline: 2.7851x; 1.5391x over previous
//
#include <hip/hip_runtime.h>

#define NMF_EPS 1e-6f

typedef unsigned short ushort_t;
typedef __attribute__((ext_vector_type(8))) short bf16x8;
typedef __attribute__((ext_vector_type(4))) float f32x4;

__device__ __forceinline__ ushort_t f2bf(float f) {
    unsigned int u = __float_as_uint(f);
    return (ushort_t)((u + 0x7FFFu + ((u >> 16) & 1u)) >> 16);
}
__device__ __forceinline__ float bf2f(ushort_t h) {
    return __uint_as_float(((unsigned int)h) << 16);
}

__device__ __forceinline__ void gl_lds16(const ushort_t* g, ushort_t* l) {
    __builtin_amdgcn_global_load_lds(
        (const __attribute__((address_space(1))) unsigned int*)g,
        (__attribute__((address_space(3))) unsigned int*)l,
        16, 0, 0);
}

// =====================================================================
// Big MFMA GEMM (lower / upper). C[m,n] = op(sum_k A[m,k]*B[n,k])
// EPI 2: relu(acc+bias[m]) -> bf16 hi/lo TRANSPOSED [n][M], coalesced via
//        2-pass LDS transpose (reuses staging LDS after k-loop).
// EPI 3: relu(ham*acc + sc*res[m,n]) -> fp32 [M,N]
// =====================================================================
template<int SPLIT, int EPI>
__global__ __launch_bounds__(256) void mfma_gemm(
    const ushort_t* __restrict__ Ah, const ushort_t* __restrict__ Al,
    const ushort_t* __restrict__ Bh, const ushort_t* __restrict__ Bl,
    float* __restrict__ C, ushort_t* __restrict__ Chi, ushort_t* __restrict__ Clo,
    int M, int N, int K,
    long sB, long sC,
    const float* __restrict__ bias,
    const float* __restrict__ res, long sRes,
    const float* __restrict__ hamp, const float* __restrict__ scp)
{
    __shared__ char smem[SPLIT ? 32768 : 16384];
    ushort_t* sAh = (ushort_t*)smem;
    ushort_t* sBh = (ushort_t*)(smem + 8192);
    ushort_t* sAl = SPLIT ? (ushort_t*)(smem + 16384) : nullptr;
    ushort_t* sBl = SPLIT ? (ushort_t*)(smem + 24576) : nullptr;

    const int tid  = threadIdx.x;
    const int wave = tid >> 6, lane = tid & 63;
    const int quad = lane >> 4, lr = lane & 15;
    const int batch = blockIdx.z;
    const int m0 = blockIdx.y * 128, n0 = blockIdx.x * 128;

    const ushort_t* Bhb = Bh + (long)batch * sB;
    const ushort_t* Blb = SPLIT ? (Bl + (long)batch * sB) : nullptr;

    f32x4 acc[4][4];
    #pragma unroll
    for (int i = 0; i < 4; ++i)
        #pragma unroll
        for (int j = 0; j < 4; ++j)
            acc[i][j] = (f32x4){0.f, 0.f, 0.f, 0.f};

    const int q   = wave * 2;
    const int ra0 = (q + 0) * 16 + (lane >> 2);
    const int ra1 = (q + 1) * 16 + (lane >> 2);
    const int ko  = (lane & 3) * 8;
    const int wm = (wave & 1) * 64, wn = (wave >> 1) * 64;

    for (int k0 = 0; k0 < K; k0 += 32) {
        gl_lds16(&Ah [(long)(m0 + ra0) * K + k0 + ko], &sAh[(q + 0) * 512]);
        gl_lds16(&Ah [(long)(m0 + ra1) * K + k0 + ko], &sAh[(q + 1) * 512]);
        gl_lds16(&Bhb[(long)(n0 + ra0) * K + k0 + ko], &sBh[(q + 0) * 512]);
        gl_lds16(&Bhb[(long)(n0 + ra1) * K + k0 + ko], &sBh[(q + 1) * 512]);
        if constexpr (SPLIT) {
            gl_lds16(&Al [(long)(m0 + ra0) * K + k0 + ko], &sAl[(q + 0) * 512]);
            gl_lds16(&Al [(long)(m0 + ra1) * K + k0 + ko], &sAl[(q + 1) * 512]);
            gl_lds16(&Blb[(long)(n0 + ra0) * K + k0 + ko], &sBl[(q + 0) * 512]);
            gl_lds16(&Blb[(long)(n0 + ra1) * K + k0 + ko], &sBl[(q + 1) * 512]);
        }
        __syncthreads();

        bf16x8 af[4], bfr[4], afl[4], bfl[4];
        #pragma unroll
        for (int i = 0; i < 4; ++i)
            af[i] = *(const bf16x8*)&sAh[(wm + i * 16 + lr) * 32 + quad * 8];
        #pragma unroll
        for (int j = 0; j < 4; ++j)
            bfr[j] = *(const bf16x8*)&sBh[(wn + j * 16 + lr) * 32 + quad * 8];
        if constexpr (SPLIT) {
            #pragma unroll
            for (int i = 0; i < 4; ++i)
                afl[i] = *(const bf16x8*)&sAl[(wm + i * 16 + lr) * 32 + quad * 8];
            #pragma unroll
            for (int j = 0; j < 4; ++j)
                bfl[j] = *(const bf16x8*)&sBl[(wn + j * 16 + lr) * 32 + quad * 8];
        }

        #pragma unroll
        for (int i = 0; i < 4; ++i)
            #pragma unroll
            for (int j = 0; j < 4; ++j) {
                acc[i][j] = __builtin_amdgcn_mfma_f32_16x16x32_bf16(af[i], bfr[j], acc[i][j], 0, 0, 0);
                if constexpr (SPLIT) {
                    acc[i][j] = __builtin_amdgcn_mfma_f32_16x16x32_bf16(af[i], bfl[j], acc[i][j], 0, 0, 0);
                    acc[i][j] = __builtin_amdgcn_mfma_f32_16x16x32_bf16(afl[i], bfr[j], acc[i][j], 0, 0, 0);
                }
            }
        __syncthreads();
    }

    if (EPI == 2) {
        // 2-pass LDS transpose -> coalesced bf16 hi/lo [n][M] stores
        ushort_t* Hh = Chi + (long)batch * sC;
        ushort_t* Hl = Clo + (long)batch * sC;
        unsigned int* slab = (unsigned int*)smem;  // [128][64] u32 = 32 KB
        #pragma unroll
        for (int p = 0; p < 2; ++p) {
            __syncthreads();
            if ((wave & 1) == p) {
                #pragma unroll
                for (int i = 0; i < 4; ++i) {
                    const int mb = m0 + p * 64 + i * 16 + quad * 4;
                    #pragma unroll
                    for (int j = 0; j < 4; ++j) {
                        const int nl = wn + j * 16 + lr;
                        #pragma unroll
                        for (int r = 0; r < 4; ++r) {
                            float v = fmaxf(acc[i][j][r] + bias[mb + r], 0.f);
                            ushort_t h = f2bf(v);
                            ushort_t l = f2bf(v - bf2f(h));
                            slab[nl * 64 + (i * 16 + quad * 4 + r)] =
                                (unsigned)h | ((unsigned)l << 16);
                        }
                    }
                }
            }
            __syncthreads();
            for (int idx = tid; idx < 8192; idx += 256) {
                const int nl = idx >> 6, ml = idx & 63;
                unsigned u = slab[idx];
                const long off = (long)(n0 + nl) * M + m0 + p * 64 + ml;
                Hh[off] = (ushort_t)(u & 0xffffu);
                Hl[off] = (ushort_t)(u >> 16);
            }
        }
    } else {
        const float hm = *hamp, sc = *scp;
        float* Cb = C + (long)batch * sC;
        #pragma unroll
        for (int i = 0; i < 4; ++i) {
            #pragma unroll
            for (int j = 0; j < 4; ++j) {
                const int mbase = m0 + wm + i * 16 + quad * 4;
                const int n     = n0 + wn + j * 16 + lr;
                #pragma unroll
                for (int r = 0; r < 4; ++r) {
                    float rv = res[(long)batch * sRes + (long)(mbase + r) * N + n];
                    Cb[(long)(mbase + r) * N + n] = fmaxf(fmaf(hm, acc[i][j][r], sc * rv), 0.f);
                }
            }
        }
    }
}

// =====================================================================
// Fused coef step. grid (N/64, B), 256 thr.
// MODE 0 (INIT): coef = softmax_r(X^T bases)
// MODE 1 (MU):   coef = coef * xtb / (coef@btb + eps); also writes ct hi/lo
//                and per-block ctc Gram partials (MFMA).
// =====================================================================
template<int MODE>
__global__ __launch_bounds__(256) void coef_step(
    const ushort_t* __restrict__ Xh, const ushort_t* __restrict__ Xl,   // [B][N][512]
    const ushort_t* __restrict__ bth, const ushort_t* __restrict__ btl, // [B][64][512]
    const float* __restrict__ btb_part,   // [8][B][4096]
    float* __restrict__ coef,             // [B][N][64]
    ushort_t* __restrict__ cth, ushort_t* __restrict__ ctl, // [B][64][N]
    float* __restrict__ ctc_part,         // [64][B][4096]
    int Bcnt)
{
    __shared__ char smem[16384 + 4 * 9216];
    ushort_t* stg   = (ushort_t*)smem;                    // 4 bufs x 2048 ushorts
    ushort_t* btbLh = (ushort_t*)(smem + 16384);          // [64][72]
    ushort_t* btbLl = btbLh + 64 * 72;
    ushort_t* cfLh  = (ushort_t*)(smem + 16384 + 18432);  // [64][72]
    ushort_t* cfLl  = cfLh + 64 * 72;

    const int tid = threadIdx.x, wave = tid >> 6, lane = tid & 63;
    const int quad = lane >> 4, lr = lane & 15;
    const int b = blockIdx.y, n0 = blockIdx.x * 64;

    const ushort_t* Xhb  = Xh  + (long)b * 2097152 + (long)n0 * 512;
    const ushort_t* Xlb  = Xl  + (long)b * 2097152 + (long)n0 * 512;
    const ushort_t* bthb = bth + (long)b * 32768;
    const ushort_t* btlb = btl + (long)b * 32768;
    float* coefB = coef + (long)b * 262144 + (long)n0 * 64;

    if (MODE == 1) {
        for (int i = tid; i < 4096; i += 256) {
            const int r = i >> 6, s = i & 63;
            float v = 0.f;
            #pragma unroll
            for (int c = 0; c < 8; ++c)
                v += btb_part[((long)c * Bcnt + b) * 4096 + i];
            ushort_t h = f2bf(v);
            btbLh[r * 72 + s] = h;
            btbLl[r * 72 + s] = f2bf(v - bf2f(h));
            float cv = coefB[i];
            ushort_t ch = f2bf(cv);
            cfLh[r * 72 + s] = ch;
            cfLl[r * 72 + s] = f2bf(cv - bf2f(ch));
        }
    }

    // ---- xtb via MFMA (split), never materialized ----
    const int srow = wave * 16 + (lane >> 2);
    const int koff = (lane & 3) * 8;
    f32x4 accx[4];
    #pragma unroll
    for (int j = 0; j < 4; ++j) accx[j] = (f32x4){0.f, 0.f, 0.f, 0.f};

    for (int kt = 0; kt < 512; kt += 32) {
        gl_lds16(&Xhb [(long)srow * 512 + kt + koff], &stg[0 * 2048 + wave * 512]);
        gl_lds16(&Xlb [(long)srow * 512 + kt + koff], &stg[1 * 2048 + wave * 512]);
        gl_lds16(&bthb[(long)srow * 512 + kt + koff], &stg[2 * 2048 + wave * 512]);
        gl_lds16(&btlb[(long)srow * 512 + kt + koff], &stg[3 * 2048 + wave * 512]);
        __syncthreads();
        bf16x8 ah = *(const bf16x8*)&stg[0 * 2048 + (wave * 16 + lr) * 32 + quad * 8];
        bf16x8 al = *(const bf16x8*)&stg[1 * 2048 + (wave * 16 + lr) * 32 + quad * 8];
        #pragma unroll
        for (int j = 0; j < 4; ++j) {
            bf16x8 bh = *(const bf16x8*)&stg[2 * 2048 + (j * 16 + lr) * 32 + quad * 8];
            bf16x8 bl = *(const bf16x8*)&stg[3 * 2048 + (j * 16 + lr) * 32 + quad * 8];
            accx[j] = __builtin_amdgcn_mfma_f32_16x16x32_bf16(ah, bh, accx[j], 0, 0, 0);
            accx[j] = __builtin_amdgcn_mfma_f32_16x16x32_bf16(ah, bl, accx[j], 0, 0, 0);
            accx[j] = __builtin_amdgcn_mfma_f32_16x16x32_bf16(al, bh, accx[j], 0, 0, 0);
        }
        __syncthreads();
    }

    float cnew[4][4]; // [j][reg]
    if (MODE == 1) {
        f32x4 accd[4];
        #pragma unroll
        for (int j = 0; j < 4; ++j) accd[j] = (f32x4){0.f, 0.f, 0.f, 0.f};
        #pragma unroll
        for (int kk = 0; kk < 64; kk += 32) {
            bf16x8 ah = *(const bf16x8*)&cfLh[(wave * 16 + lr) * 72 + kk + quad * 8];
            bf16x8 al = *(const bf16x8*)&cfLl[(wave * 16 + lr) * 72 + kk + quad * 8];
            #pragma unroll
            for (int j = 0; j < 4; ++j) {
                bf16x8 bh = *(const bf16x8*)&btbLh[(j * 16 + lr) * 72 + kk + quad * 8];
                bf16x8 bl = *(const bf16x8*)&btbLl[(j * 16 + lr) * 72 + kk + quad * 8];
                accd[j] = __builtin_amdgcn_mfma_f32_16x16x32_bf16(ah, bh, accd[j], 0, 0, 0);
                accd[j] = __builtin_amdgcn_mfma_f32_16x16x32_bf16(ah, bl, accd[j], 0, 0, 0);
                accd[j] = __builtin_amdgcn_mfma_f32_16x16x32_bf16(al, bh, accd[j], 0, 0, 0);
            }
        }
        #pragma unroll
        for (int j = 0; j < 4; ++j)
            #pragma unroll
            for (int r = 0; r < 4; ++r) {
                float cold = coefB[(wave * 16 + quad * 4 + r) * 64 + j * 16 + lr];
                cnew[j][r] = cold * accx[j][r] / (accd[j][r] + NMF_EPS);
            }
    } else {
        #pragma unroll
        for (int r = 0; r < 4; ++r) {
            float m = fmaxf(fmaxf(accx[0][r], accx[1][r]), fmaxf(accx[2][r], accx[3][r]));
            #pragma unroll
            for (int off = 1; off < 16; off <<= 1) m = fmaxf(m, __shfl_xor(m, off, 64));
            float e[4], s = 0.f;
            #pragma unroll
            for (int j = 0; j < 4; ++j) { e[j] = __expf(accx[j][r] - m); s += e[j]; }
            #pragma unroll
            for (int off = 1; off < 16; off <<= 1) s += __shfl_xor(s, off, 64);
            float inv = 1.f / s;
            #pragma unroll
            for (int j = 0; j < 4; ++j) cnew[j][r] = e[j] * inv;
        }
    }

    #pragma unroll
    for (int j = 0; j < 4; ++j)
        #pragma unroll
        for (int r = 0; r < 4; ++r)
            coefB[(wave * 16 + quad * 4 + r) * 64 + j * 16 + lr] = cnew[j][r];

    if (MODE == 0) return;

    __syncthreads();  // cfL dead; overlay ct
    ushort_t* ctLh = cfLh;
    ushort_t* ctLl = cfLl;
    #pragma unroll
    for (int j = 0; j < 4; ++j)
        #pragma unroll
        for (int r = 0; r < 4; ++r) {
            const int nl = wave * 16 + quad * 4 + r;
            const int rr = j * 16 + lr;
            float v = cnew[j][r];
            ushort_t h = f2bf(v);
            ctLh[rr * 72 + nl] = h;
            ctLl[rr * 72 + nl] = f2bf(v - bf2f(h));
        }
    __syncthreads();
    for (int i = tid; i < 4096; i += 256) {
        const int r = i >> 6, nn = i & 63;
        cth[(long)b * 262144 + (long)r * 4096 + n0 + nn] = ctLh[r * 72 + nn];
        ctl[(long)b * 262144 + (long)r * 4096 + n0 + nn] = ctLl[r * 72 + nn];
    }
    // ctc Gram partials via MFMA
    f32x4 accc[4];
    #pragma unroll
    for (int j = 0; j < 4; ++j) accc[j] = (f32x4){0.f, 0.f, 0.f, 0.f};
    #pragma unroll
    for (int kk = 0; kk < 64; kk += 32) {
        bf16x8 ah = *(const bf16x8*)&ctLh[(wave * 16 + lr) * 72 + kk + quad * 8];
        bf16x8 al = *(const bf16x8*)&ctLl[(wave * 16 + lr) * 72 + kk + quad * 8];
        #pragma unroll
        for (int j = 0; j < 4; ++j) {
            bf16x8 bh = *(const bf16x8*)&ctLh[(j * 16 + lr) * 72 + kk + quad * 8];
            bf16x8 bl = *(const bf16x8*)&ctLl[(j * 16 + lr) * 72 + kk + quad * 8];
            accc[j] = __builtin_amdgcn_mfma_f32_16x16x32_bf16(ah, bh, accc[j], 0, 0, 0);
            accc[j] = __builtin_amdgcn_mfma_f32_16x16x32_bf16(ah, bl, accc[j], 0, 0, 0);
            accc[j] = __builtin_amdgcn_mfma_f32_16x16x32_bf16(al, bh, accc[j], 0, 0, 0);
        }
    }
    float* cp = ctc_part + ((long)blockIdx.x * Bcnt + b) * 4096;
    #pragma unroll
    for (int j = 0; j < 4; ++j)
        #pragma unroll
        for (int r = 0; r < 4; ++r)
            cp[(wave * 16 + quad * 4 + r) * 64 + j * 16 + lr] = accc[j][r];
}

// reduce ctc partials: ctc[b][i] = sum over 64 n-chunks
__global__ __launch_bounds__(256) void ctc_reduce(const float* __restrict__ part,
                                                  float* __restrict__ ctc, int Bcnt)
{
    const int b = blockIdx.x >> 4;
    const int i = (blockIdx.x & 15) * 256 + threadIdx.x;
    float v = 0.f;
    #pragma unroll 8
    for (int c = 0; c < 64; ++c)
        v += part[((long)c * Bcnt + b) * 4096 + i];
    ctc[(long)b * 4096 + i] = v;
}

// xc split-K partials: part[kc][b][c][r] = sum_{k in chunk} X[c,k]*coef_t[r,k]
// grid (8, C/64, B)
__global__ __launch_bounds__(256) void xc_partial(
    const ushort_t* __restrict__ Ah, const ushort_t* __restrict__ Al, // X_dn [B][512][4096]
    const ushort_t* __restrict__ Bh, const ushort_t* __restrict__ Bl, // ct  [B][64][4096]
    float* __restrict__ part, int Bcnt)
{
    __shared__ ushort_t sAh[2048], sAl[2048], sBh[2048], sBl[2048];
    const int tid = threadIdx.x, wave = tid >> 6, lane = tid & 63;
    const int quad = lane >> 4, lr = lane & 15;
    const int batch = blockIdx.z;
    const int m0 = blockIdx.y * 64;
    const int k0 = blockIdx.x * 512;

    const ushort_t* Ab  = Ah + (long)batch * 2097152;
    const ushort_t* Alb = Al + (long)batch * 2097152;
    const ushort_t* Bb  = Bh + (long)batch * 262144;
    const ushort_t* Blb = Bl + (long)batch * 262144;

    const int srow = wave * 16 + (lane >> 2);
    const int koff = (lane & 3) * 8;

    f32x4 acc[4];
    #pragma unroll
    for (int j = 0; j < 4; ++j) acc[j] = (f32x4){0.f, 0.f, 0.f, 0.f};

    for (int kt = 0; kt < 512; kt += 32) {
        gl_lds16(&Ab [(long)(m0 + srow) * 4096 + k0 + kt + koff], &sAh[wave * 512]);
        gl_lds16(&Alb[(long)(m0 + srow) * 4096 + k0 + kt + koff], &sAl[wave * 512]);
        gl_lds16(&Bb [(long)srow * 4096 + k0 + kt + koff], &sBh[wave * 512]);
        gl_lds16(&Blb[(long)srow * 4096 + k0 + kt + koff], &sBl[wave * 512]);
        __syncthreads();
        bf16x8 ah = *(const bf16x8*)&sAh[(wave * 16 + lr) * 32 + quad * 8];
        bf16x8 al = *(const bf16x8*)&sAl[(wave * 16 + lr) * 32 + quad * 8];
        #pragma unroll
        for (int j = 0; j < 4; ++j) {
            bf16x8 bh = *(const bf16x8*)&sBh[(j * 16 + lr) * 32 + quad * 8];
            bf16x8 bl = *(const bf16x8*)&sBl[(j * 16 + lr) * 32 + quad * 8];
            acc[j] = __builtin_amdgcn_mfma_f32_16x16x32_bf16(ah, bh, acc[j], 0, 0, 0);
            acc[j] = __builtin_amdgcn_mfma_f32_16x16x32_bf16(ah, bl, acc[j], 0, 0, 0);
            acc[j] = __builtin_amdgcn_mfma_f32_16x16x32_bf16(al, bh, acc[j], 0, 0, 0);
        }
        __syncthreads();
    }

    float* Cb = part + ((long)blockIdx.x * Bcnt + batch) * 32768;
    #pragma unroll
    for (int j = 0; j < 4; ++j) {
        const int col = j * 16 + lr;
        #pragma unroll
        for (int r = 0; r < 4; ++r)
            Cb[(long)(m0 + wave * 16 + quad * 4 + r) * 64 + col] = acc[j][r];
    }
}

// =====================================================================
// Fused bases step. grid (C/64, B).
// MODE 0 (prep): bases -> bt hi/lo + btb Gram partials
// MODE 1 (full): reduce xc partials, mu-update bases, then bt + btb partials
// =====================================================================
template<int MODE>
__global__ __launch_bounds__(256) void bases_step(
    const float* __restrict__ xc_part,   // [8][B][512][64]
    const float* __restrict__ ctc,       // [B][64][64]
    float* __restrict__ bases,           // [B][512][64]
    ushort_t* __restrict__ bth, ushort_t* __restrict__ btl, // [B][64][512]
    float* __restrict__ btb_part,        // [8][B][4096]
    int Bcnt)
{
    __shared__ char smem[16640 * 2 + 18432];
    float* bnL  = (float*)smem;                  // [64][65]
    float* ctcL = (float*)(smem + 16640);        // [64][65]
    ushort_t* btLh = (ushort_t*)(smem + 33280);  // [64][72]
    ushort_t* btLl = btLh + 64 * 72;
    float* basesL = (float*)(smem + 33280);      // overlays btL (phase 1 only)

    const int b = blockIdx.y, c0 = blockIdx.x * 64;
    const int tid = threadIdx.x;
    float* basesB = bases + (long)b * 32768 + (long)c0 * 64;

    if (MODE == 1) {
        for (int i = tid; i < 4096; i += 256) {
            const int c = i >> 6, r = i & 63;
            basesL[c * 65 + r] = basesB[i];
            ctcL[c * 65 + r]   = ctc[(long)b * 4096 + i];
            float v = 0.f;
            #pragma unroll
            for (int s0 = 0; s0 < 8; ++s0)
                v += xc_part[((long)s0 * Bcnt + b) * 32768 + (long)(c0 + c) * 64 + r];
            bnL[c * 65 + r] = v;
        }
        __syncthreads();
        for (int i = tid; i < 4096; i += 256) {
            const int c = i >> 6, r = i & 63;
            float denom = 0.f;
            #pragma unroll 8
            for (int s = 0; s < 64; ++s)
                denom = fmaf(basesL[c * 65 + s], ctcL[s * 65 + r], denom);
            float bnew = basesL[c * 65 + r] * bnL[c * 65 + r] / (denom + NMF_EPS);
            bnL[c * 65 + r] = bnew;
            basesB[i] = bnew;
        }
        __syncthreads();
    } else {
        for (int i = tid; i < 4096; i += 256)
            bnL[(i >> 6) * 65 + (i & 63)] = basesB[i];
        __syncthreads();
    }

    // bt hi/lo (LDS transposed + global)
    for (int i = tid; i < 4096; i += 256) {
        const int r = i >> 6, cc = i & 63;
        float v = bnL[cc * 65 + r];
        ushort_t h = f2bf(v);
        ushort_t l = f2bf(v - bf2f(h));
        btLh[r * 72 + cc] = h;
        btLl[r * 72 + cc] = l;
        bth[(long)b * 32768 + (long)r * 512 + c0 + cc] = h;
        btl[(long)b * 32768 + (long)r * 512 + c0 + cc] = l;
    }
    __syncthreads();

    // btb Gram partials via MFMA
    const int wave = tid >> 6, lane = tid & 63;
    const int quad = lane >> 4, lr = lane & 15;
    f32x4 acg[4];
    #pragma unroll
    for (int j = 0; j < 4; ++j) acg[j] = (f32x4){0.f, 0.f, 0.f, 0.f};
    #pragma unroll
    for (int kk = 0; kk < 64; kk += 32) {
        bf16x8 ah = *(const bf16x8*)&btLh[(wave * 16 + lr) * 72 + kk + quad * 8];
        bf16x8 al = *(const bf16x8*)&btLl[(wave * 16 + lr) * 72 + kk + quad * 8];
        #pragma unroll
        for (int j = 0; j < 4; ++j) {
            bf16x8 bh = *(const bf16x8*)&btLh[(j * 16 + lr) * 72 + kk + quad * 8];
            bf16x8 bl = *(const bf16x8*)&btLl[(j * 16 + lr) * 72 + kk + quad * 8];
            acg[j] = __builtin_amdgcn_mfma_f32_16x16x32_bf16(ah, bh, acg[j], 0, 0, 0);
            acg[j] = __builtin_amdgcn_mfma_f32_16x16x32_bf16(ah, bl, acg[j], 0, 0, 0);
            acg[j] = __builtin_amdgcn_mfma_f32_16x16x32_bf16(al, bh, acg[j], 0, 0, 0);
        }
    }
    float* gp = btb_part + ((long)blockIdx.x * Bcnt + b) * 4096;
    #pragma unroll
    for (int j = 0; j < 4; ++j)
        #pragma unroll
        for (int r = 0; r < 4; ++r)
            gp[(wave * 16 + quad * 4 + r) * 64 + j * 16 + lr] = acg[j][r];
}

// =====================================================================
// fp32 tiled GEMM (cheese ops only): EPI 0 plain; 4 relu(+bias)->bf16 [n][m]
// =====================================================================
constexpr int BM = 64, BN = 64, BK = 16;

template<int ALAY, int BLAY, int EPI>
__global__ __launch_bounds__(256) void gemm_kernel(
    const float* __restrict__ A, const float* __restrict__ B, float* __restrict__ C,
    int Kchunk, int kchunks,
    int lda, int ldb, int ldc,
    long sA, long sB, long sC,
    const float* __restrict__ bias)
{
    __shared__ float As[BK][BM + 4];
    __shared__ float Bs[BK][BN + 4];

    const int batch = blockIdx.z;
    const float* Ab = A + (long)batch * sA;
    const float* Bb = B + (long)batch * sB;

    const int m0  = blockIdx.y * BM;
    const int n0  = blockIdx.x * BN;
    const int tid = threadIdx.x;
    const int ty  = tid >> 4, tx = tid & 15;

    float acc[4][4] = {};

    for (int kt = 0; kt < Kchunk; kt += BK) {
        if (ALAY == 0) {
            const int m = tid >> 2, k4 = (tid & 3) << 2;
            float4 v = *(const float4*)&Ab[(long)(m0 + m) * lda + (kt + k4)];
            As[k4 + 0][m] = v.x; As[k4 + 1][m] = v.y;
            As[k4 + 2][m] = v.z; As[k4 + 3][m] = v.w;
        } else {
            const int k = tid >> 4, m4 = (tid & 15) << 2;
            float4 v = *(const float4*)&Ab[(long)(kt + k) * lda + (m0 + m4)];
            *(float4*)&As[k][m4] = v;
        }
        if (BLAY == 0) {
            const int k = tid >> 4, n4 = (tid & 15) << 2;
            float4 v = *(const float4*)&Bb[(long)(kt + k) * ldb + (n0 + n4)];
            *(float4*)&Bs[k][n4] = v;
        } else {
            const int n = tid >> 2, k4 = (tid & 3) << 2;
            float4 v = *(const float4*)&Bb[(long)(n0 + n) * ldb + (kt + k4)];
            Bs[k4 + 0][n] = v.x; Bs[k4 + 1][n] = v.y;
            Bs[k4 + 2][n] = v.z; Bs[k4 + 3][n] = v.w;
        }
        __syncthreads();
        #pragma unroll
        for (int k = 0; k < BK; ++k) {
            float4 a4 = *(const float4*)&As[k][ty << 2];
            float4 b4 = *(const float4*)&Bs[k][tx << 2];
            float av[4] = {a4.x, a4.y, a4.z, a4.w};
            float bv[4] = {b4.x, b4.y, b4.z, b4.w};
            #pragma unroll
            for (int i = 0; i < 4; ++i)
                #pragma unroll
                for (int j = 0; j < 4; ++j)
                    acc[i][j] = fmaf(av[i], bv[j], acc[i][j]);
        }
        __syncthreads();
    }

    const int mb = m0 + (ty << 2), nb = n0 + (tx << 2);
    if (EPI == 4) {
        ushort_t* Cu = (ushort_t*)C + (long)batch * sC;
        #pragma unroll
        for (int j = 0; j < 4; ++j) {
            ushort_t pk[4];
            #pragma unroll
            for (int i = 0; i < 4; ++i)
                pk[i] = f2bf(fmaxf(acc[i][j] + bias[mb + i], 0.f));
            *(ushort4*)&Cu[(long)(nb + j) * ldc + mb] =
                make_ushort4(pk[0], pk[1], pk[2], pk[3]);
        }
    } else {
        float* Cb = C + (long)batch * sC;
        #pragma unroll
        for (int i = 0; i < 4; ++i) {
            float4 o = make_float4(acc[i][0], acc[i][1], acc[i][2], acc[i][3]);
            *(float4*)&Cb[(long)(mb + i) * ldc + nb] = o;
        }
    }
}

// ---------- casts / transposes ----------
__global__ __launch_bounds__(256) void cast_x_t(const float* __restrict__ x,
                                                ushort_t* __restrict__ hi,
                                                ushort_t* __restrict__ lo)
{
    __shared__ float t[64][65];
    const int b = blockIdx.z, c0 = blockIdx.y * 64, n0 = blockIdx.x * 64;
    const int tid = threadIdx.x, tx = tid & 63, ty = tid >> 6;
    const float* xb = x + (long)b * 512 * 4096;
    #pragma unroll 4
    for (int s = ty; s < 64; s += 4)
        t[s][tx] = xb[(long)(c0 + s) * 4096 + n0 + tx];
    __syncthreads();
    #pragma unroll 4
    for (int s = ty; s < 64; s += 4) {
        float v = t[tx][s];
        long idx = (long)b * 2097152 + (long)(n0 + s) * 512 + c0 + tx;
        ushort_t h = f2bf(v);
        hi[idx] = h;
        lo[idx] = f2bf(v - bf2f(h));
    }
}

__global__ __launch_bounds__(256) void nd2dn(const ushort_t* __restrict__ hi,
                                             const ushort_t* __restrict__ lo,
                                             ushort_t* __restrict__ dhi,
                                             ushort_t* __restrict__ dlo)
{
    __shared__ unsigned int t[64][65];
    const int b = blockIdx.z, n0 = blockIdx.x * 64, c0 = blockIdx.y * 64;
    const int tx = threadIdx.x & 63, ty = threadIdx.x >> 6;
    const long base = (long)b * 2097152;
    #pragma unroll 4
    for (int s = ty; s < 64; s += 4) {
        long idx = base + (long)(n0 + s) * 512 + c0 + tx;
        t[s][tx] = (unsigned)hi[idx] | ((unsigned)lo[idx] << 16);
    }
    __syncthreads();
    #pragma unroll 4
    for (int s = ty; s < 64; s += 4) {
        unsigned v = t[tx][s];
        long idx = base + (long)(c0 + s) * 4096 + n0 + tx;
        dhi[idx] = (ushort_t)(v & 0xffffu);
        dlo[idx] = (ushort_t)(v >> 16);
    }
}

__global__ void cast_w_split(const float* __restrict__ w, ushort_t* __restrict__ hi,
                             ushort_t* __restrict__ lo, int n)
{
    int i = blockIdx.x * 256 + threadIdx.x;
    if (i < n) {
        float v = w[i];
        ushort_t h = f2bf(v);
        hi[i] = h;
        lo[i] = f2bf(v - bf2f(h));
    }
}

__global__ void cast_w_plain(const float* __restrict__ w, ushort_t* __restrict__ o, int n)
{
    int i = blockIdx.x * 256 + threadIdx.x;
    if (i < n) o[i] = f2bf(w[i]);
}

__global__ __launch_bounds__(1024) void l2norm_kernel(const float* __restrict__ b0,
                                                      float* __restrict__ bases)
{
    __shared__ float part[16][64];
    const int b = blockIdx.x;
    const int tid = threadIdx.x;
    const int r = tid & 63, slice = tid >> 6;
    const float* src = b0 + (long)b * 512 * 64;
    float* dst = bases + (long)b * 512 * 64;
    float s = 0.f;
    #pragma unroll 4
    for (int d = slice; d < 512; d += 16) {
        float v = src[d * 64 + r];
        s = fmaf(v, v, s);
    }
    part[slice][r] = s;
    __syncthreads();
    if (slice == 0) {
        float t = 0.f;
        #pragma unroll
        for (int i = 0; i < 16; ++i) t += part[i][r];
        part[0][r] = 1.0f / fmaxf(sqrtf(t), 1e-12f);
    }
    __syncthreads();
    const float inv = part[0][r];
    #pragma unroll 4
    for (int d = slice; d < 512; d += 16)
        dst[d * 64 + r] = src[d * 64 + r] * inv;
}

extern "C" void kernel_launch(void* const* d_in, const int* in_sizes, int n_in,
                              void* d_out, int out_size, void* d_ws, size_t ws_size,
                              hipStream_t stream)
{
    const float* x_in     = (const float*)d_in[0];
    const float* bases0   = (const float*)d_in[1];
    const float* w_lower  = (const float*)d_in[2];
    const float* b_lower  = (const float*)d_in[3];
    const float* w_cheese = (const float*)d_in[4];
    const float* b_cheese = (const float*)d_in[5];
    const float* w_upper  = (const float*)d_in[6];
    const float* csc      = (const float*)d_in[7];
    const float* cham     = (const float*)d_in[8];
    float* out = (float*)d_out;

    const int B = 8, C = 512, N = 4096, R = 64;
    const long sCN = (long)C * N;
    const long sNC = (long)N * C;
    const long sNR = (long)N * R, sCR = (long)C * R;

    // ---- workspace layout (bytes, ~141 MB) ----
    char* w = (char*)d_ws;
    ushort_t* X_nd_hi  = (ushort_t*)w;  w += 33554432;  // [B,N,C]
    ushort_t* xt_hi    = (ushort_t*)w;  w += 33554432;  // x^T; later X_dn_hi
    ushort_t* xt_lo    = (ushort_t*)w;  w += 33554432;  // x^T; later X_dn_lo
    float*    coef     = (float*)w;     w += 8388608;   // [B,N,R]
    ushort_t* ct_hi    = (ushort_t*)w;  w += 4194304;   // [B,R,N]
    ushort_t* ct_lo    = (ushort_t*)w;  w += 4194304;
    float*    ctc_part = (float*)w;     w += 8388608;   // [64][B][4096]
    float*    xc_part  = (float*)w;     w += 8388608;   // [8][B][512][64]
    float*    btb_part = (float*)w;     w += 1048576;   // [8][B][4096]
    float*    bases    = (float*)w;     w += 1048576;   // [B,C,R]
    float*    WcB      = (float*)w;     w += 1048576;   // [B,C,R]
    float*    ctc      = (float*)w;     w += 131072;    // [B,R,R]
    ushort_t* bt_hi    = (ushort_t*)w;  w += 524288;    // [B,R,C]
    ushort_t* bt_lo    = (ushort_t*)w;  w += 524288;
    ushort_t* wl_hi    = (ushort_t*)w;  w += 524288;
    ushort_t* wl_lo    = (ushort_t*)w;  w += 524288;
    ushort_t* w_up     = (ushort_t*)w;  w += 524288;

    ushort_t* X_nd_lo  = (ushort_t*)d_out;  // dead before final out write
    ushort_t* X_dn_hi  = xt_hi;
    ushort_t* X_dn_lo  = xt_lo;
    ushort_t* cheese_t = X_nd_hi;           // X_nd dead after final coef_step

    const dim3 blk(256);

    // init
    l2norm_kernel<<<dim3(B), dim3(1024), 0, stream>>>(bases0, bases);
    bases_step<0><<<dim3(C / 64, B), blk, 0, stream>>>(
        nullptr, nullptr, bases, bt_hi, bt_lo, btb_part, B);
    cast_w_split<<<dim3(1024), blk, 0, stream>>>(w_lower, wl_hi, wl_lo, C * C);
    cast_w_plain<<<dim3(1024), blk, 0, stream>>>(w_upper, w_up, C * C);
    cast_x_t<<<dim3(N / 64, C / 64, B), blk, 0, stream>>>(x_in, xt_hi, xt_lo);

    // X = relu(w_lower @ x + b_lower) -> bf16 hi/lo [n][c]
    mfma_gemm<1, 2><<<dim3(N / 128, C / 128, B), blk, 0, stream>>>(
        wl_hi, wl_lo, xt_hi, xt_lo, nullptr, X_nd_hi, X_nd_lo,
        C, N, C, sNC, sNC, b_lower, nullptr, 0L, nullptr, nullptr);
    nd2dn<<<dim3(N / 64, C / 64, B), blk, 0, stream>>>(X_nd_hi, X_nd_lo, X_dn_hi, X_dn_lo);

    // coef init (softmax)
    coef_step<0><<<dim3(N / 64, B), blk, 0, stream>>>(
        X_nd_hi, X_nd_lo, bt_hi, bt_lo, btb_part, coef, ct_hi, ct_lo, ctc_part, B);

    for (int step = 0; step < 6; ++step) {
        coef_step<1><<<dim3(N / 64, B), blk, 0, stream>>>(
            X_nd_hi, X_nd_lo, bt_hi, bt_lo, btb_part, coef, ct_hi, ct_lo, ctc_part, B);
        ctc_reduce<<<dim3(B * 16), blk, 0, stream>>>(ctc_part, ctc, B);
        xc_partial<<<dim3(8, C / 64, B), blk, 0, stream>>>(
            X_dn_hi, X_dn_lo, ct_hi, ct_lo, xc_part, B);
        bases_step<1><<<dim3(C / 64, B), blk, 0, stream>>>(
            xc_part, ctc, bases, bt_hi, bt_lo, btb_part, B);
    }

    // final differentiable coef refinement
    coef_step<1><<<dim3(N / 64, B), blk, 0, stream>>>(
        X_nd_hi, X_nd_lo, bt_hi, bt_lo, btb_part, coef, ct_hi, ct_lo, ctc_part, B);

    // cheese via associativity
    gemm_kernel<0, 0, 0><<<dim3(1, C / BM, B), blk, 0, stream>>>(
        w_cheese, bases, WcB, C, 1, C, R, R, 0L, sCR, sCR, nullptr);
    gemm_kernel<0, 1, 4><<<dim3(N / BN, C / BM, B), blk, 0, stream>>>(
        WcB, coef, (float*)cheese_t, R, 1, R, R, C, sCR, sNR, sNC, b_cheese);

    // out = relu(ham * (w_upper @ cheese) + sc * x)
    mfma_gemm<0, 3><<<dim3(N / 128, C / 128, B), blk, 0, stream>>>(
        w_up, nullptr, cheese_t, nullptr, out, nullptr, nullptr,
        C, N, C, sNC, sCN, nullptr, x_in, sCN, cham, csc);
}

// Round 6
// 755.476 us; speedup vs baseline: 2.9358x; 1.0541x over previous
//
#include <hip/hip_runtime.h>

#define NMF_EPS 1e-6f

typedef unsigned short ushort_t;
typedef __attribute__((ext_vector_type(8))) short bf16x8;
typedef __attribute__((ext_vector_type(4))) float f32x4;

__device__ __forceinline__ ushort_t f2bf(float f) {
    unsigned int u = __float_as_uint(f);
    return (ushort_t)((u + 0x7FFFu + ((u >> 16) & 1u)) >> 16);
}
__device__ __forceinline__ float bf2f(ushort_t h) {
    return __uint_as_float(((unsigned int)h) << 16);
}

__device__ __forceinline__ void gl_lds16(const ushort_t* g, ushort_t* l) {
    __builtin_amdgcn_global_load_lds(
        (const __attribute__((address_space(1))) unsigned int*)g,
        (__attribute__((address_space(3))) unsigned int*)l,
        16, 0, 0);
}

// =====================================================================
// Big MFMA GEMM (lower / upper). C[m,n] = op(sum_k A[m,k]*B[n,k])
// EPI 2: relu(acc+bias[m]) -> bf16 hi/lo TRANSPOSED [n][M] (LDS transpose)
// EPI 3: relu(ham*acc + sc*res[m,n]) -> fp32 [M,N]
// =====================================================================
template<int SPLIT, int EPI>
__global__ __launch_bounds__(256) void mfma_gemm(
    const ushort_t* __restrict__ Ah, const ushort_t* __restrict__ Al,
    const ushort_t* __restrict__ Bh, const ushort_t* __restrict__ Bl,
    float* __restrict__ C, ushort_t* __restrict__ Chi, ushort_t* __restrict__ Clo,
    int M, int N, int K,
    long sB, long sC,
    const float* __restrict__ bias,
    const float* __restrict__ res, long sRes,
    const float* __restrict__ hamp, const float* __restrict__ scp)
{
    __shared__ char smem[SPLIT ? 32768 : 16384];
    ushort_t* sAh = (ushort_t*)smem;
    ushort_t* sBh = (ushort_t*)(smem + 8192);
    ushort_t* sAl = SPLIT ? (ushort_t*)(smem + 16384) : nullptr;
    ushort_t* sBl = SPLIT ? (ushort_t*)(smem + 24576) : nullptr;

    const int tid  = threadIdx.x;
    const int wave = tid >> 6, lane = tid & 63;
    const int quad = lane >> 4, lr = lane & 15;
    const int batch = blockIdx.z;
    const int m0 = blockIdx.y * 128, n0 = blockIdx.x * 128;

    const ushort_t* Bhb = Bh + (long)batch * sB;
    const ushort_t* Blb = SPLIT ? (Bl + (long)batch * sB) : nullptr;

    f32x4 acc[4][4];
    #pragma unroll
    for (int i = 0; i < 4; ++i)
        #pragma unroll
        for (int j = 0; j < 4; ++j)
            acc[i][j] = (f32x4){0.f, 0.f, 0.f, 0.f};

    const int q   = wave * 2;
    const int ra0 = (q + 0) * 16 + (lane >> 2);
    const int ra1 = (q + 1) * 16 + (lane >> 2);
    const int ko  = (lane & 3) * 8;
    const int wm = (wave & 1) * 64, wn = (wave >> 1) * 64;

    for (int k0 = 0; k0 < K; k0 += 32) {
        gl_lds16(&Ah [(long)(m0 + ra0) * K + k0 + ko], &sAh[(q + 0) * 512]);
        gl_lds16(&Ah [(long)(m0 + ra1) * K + k0 + ko], &sAh[(q + 1) * 512]);
        gl_lds16(&Bhb[(long)(n0 + ra0) * K + k0 + ko], &sBh[(q + 0) * 512]);
        gl_lds16(&Bhb[(long)(n0 + ra1) * K + k0 + ko], &sBh[(q + 1) * 512]);
        if constexpr (SPLIT) {
            gl_lds16(&Al [(long)(m0 + ra0) * K + k0 + ko], &sAl[(q + 0) * 512]);
            gl_lds16(&Al [(long)(m0 + ra1) * K + k0 + ko], &sAl[(q + 1) * 512]);
            gl_lds16(&Blb[(long)(n0 + ra0) * K + k0 + ko], &sBl[(q + 0) * 512]);
            gl_lds16(&Blb[(long)(n0 + ra1) * K + k0 + ko], &sBl[(q + 1) * 512]);
        }
        __syncthreads();

        bf16x8 af[4], bfr[4], afl[4], bfl[4];
        #pragma unroll
        for (int i = 0; i < 4; ++i)
            af[i] = *(const bf16x8*)&sAh[(wm + i * 16 + lr) * 32 + quad * 8];
        #pragma unroll
        for (int j = 0; j < 4; ++j)
            bfr[j] = *(const bf16x8*)&sBh[(wn + j * 16 + lr) * 32 + quad * 8];
        if constexpr (SPLIT) {
            #pragma unroll
            for (int i = 0; i < 4; ++i)
                afl[i] = *(const bf16x8*)&sAl[(wm + i * 16 + lr) * 32 + quad * 8];
            #pragma unroll
            for (int j = 0; j < 4; ++j)
                bfl[j] = *(const bf16x8*)&sBl[(wn + j * 16 + lr) * 32 + quad * 8];
        }

        #pragma unroll
        for (int i = 0; i < 4; ++i)
            #pragma unroll
            for (int j = 0; j < 4; ++j) {
                acc[i][j] = __builtin_amdgcn_mfma_f32_16x16x32_bf16(af[i], bfr[j], acc[i][j], 0, 0, 0);
                if constexpr (SPLIT) {
                    acc[i][j] = __builtin_amdgcn_mfma_f32_16x16x32_bf16(af[i], bfl[j], acc[i][j], 0, 0, 0);
                    acc[i][j] = __builtin_amdgcn_mfma_f32_16x16x32_bf16(afl[i], bfr[j], acc[i][j], 0, 0, 0);
                }
            }
        __syncthreads();
    }

    if (EPI == 2) {
        ushort_t* Hh = Chi + (long)batch * sC;
        ushort_t* Hl = Clo + (long)batch * sC;
        unsigned int* slab = (unsigned int*)smem;  // [128 n][64 m] u32
        #pragma unroll
        for (int p = 0; p < 2; ++p) {
            __syncthreads();
            if ((wave & 1) == p) {
                #pragma unroll
                for (int i = 0; i < 4; ++i) {
                    const int mb = m0 + p * 64 + i * 16 + quad * 4;
                    #pragma unroll
                    for (int j = 0; j < 4; ++j) {
                        const int nl = wn + j * 16 + lr;
                        #pragma unroll
                        for (int r = 0; r < 4; ++r) {
                            float v = fmaxf(acc[i][j][r] + bias[mb + r], 0.f);
                            ushort_t h = f2bf(v);
                            ushort_t l = f2bf(v - bf2f(h));
                            slab[nl * 64 + (i * 16 + quad * 4 + r)] =
                                (unsigned)h | ((unsigned)l << 16);
                        }
                    }
                }
            }
            __syncthreads();
            for (int idx = tid; idx < 8192; idx += 256) {
                const int nl = idx >> 6, ml = idx & 63;
                unsigned u = slab[idx];
                const long off = (long)(n0 + nl) * M + m0 + p * 64 + ml;
                Hh[off] = (ushort_t)(u & 0xffffu);
                Hl[off] = (ushort_t)(u >> 16);
            }
        }
    } else {
        const float hm = *hamp, sc = *scp;
        float* Cb = C + (long)batch * sC;
        #pragma unroll
        for (int i = 0; i < 4; ++i) {
            #pragma unroll
            for (int j = 0; j < 4; ++j) {
                const int mbase = m0 + wm + i * 16 + quad * 4;
                const int n     = n0 + wn + j * 16 + lr;
                #pragma unroll
                for (int r = 0; r < 4; ++r) {
                    float rv = res[(long)batch * sRes + (long)(mbase + r) * N + n];
                    Cb[(long)(mbase + r) * N + n] = fmaxf(fmaf(hm, acc[i][j][r], sc * rv), 0.f);
                }
            }
        }
    }
}

// =====================================================================
// Fused coef step. grid (N/64, B), 256 thr. BK=64 staging (2x32k chunks
// per barrier). Denominator coef-fragments built from global fp32 (no LDS).
// MODE 0 (INIT): coef = softmax_r(X^T bases)
// MODE 1 (MU):   coef = coef * xtb / (coef@btb + eps); writes ct hi/lo and
//                per-block ctc Gram partials via MFMA.
// =====================================================================
template<int MODE>
__global__ __launch_bounds__(256) void coef_step(
    const ushort_t* __restrict__ Xh, const ushort_t* __restrict__ Xl,   // [B][N][512]
    const ushort_t* __restrict__ bth, const ushort_t* __restrict__ btl, // [B][64][512]
    const float* __restrict__ btb_part,   // [8][B][4096]
    float* __restrict__ coef,             // [B][N][64]
    ushort_t* __restrict__ cth, ushort_t* __restrict__ ctl, // [B][64][N]
    float* __restrict__ ctc_part,         // [64][B][4096]
    int Bcnt)
{
    __shared__ char smem[32768 + 18432];
    ushort_t* stg = (ushort_t*)smem;             // 8 bufs x 2048 ushorts (64r x 32k)
    ushort_t* gLh = (ushort_t*)(smem + 32768);   // [64][72] btb hi (later ct hi)
    ushort_t* gLl = gLh + 64 * 72;               // btb lo (later ct lo)

    const int tid = threadIdx.x, wave = tid >> 6, lane = tid & 63;
    const int quad = lane >> 4, lr = lane & 15;
    const int b = blockIdx.y, n0 = blockIdx.x * 64;

    const ushort_t* Xhb  = Xh  + (long)b * 2097152 + (long)n0 * 512;
    const ushort_t* Xlb  = Xl  + (long)b * 2097152 + (long)n0 * 512;
    const ushort_t* bthb = bth + (long)b * 32768;
    const ushort_t* btlb = btl + (long)b * 32768;
    float* coefB = coef + (long)b * 262144 + (long)n0 * 64;

    if (MODE == 1) {
        // reduce btb partials -> LDS (hi/lo)
        for (int i = tid; i < 4096; i += 256) {
            const int r = i >> 6, s = i & 63;
            float v = 0.f;
            #pragma unroll
            for (int c = 0; c < 8; ++c)
                v += btb_part[((long)c * Bcnt + b) * 4096 + i];
            ushort_t h = f2bf(v);
            gLh[r * 72 + s] = h;
            gLl[r * 72 + s] = f2bf(v - bf2f(h));
        }
    }

    // ---- xtb via MFMA, BK=64 ----
    const int srow = wave * 16 + (lane >> 2);
    const int koff = (lane & 3) * 8;
    f32x4 accx[4];
    #pragma unroll
    for (int j = 0; j < 4; ++j) accx[j] = (f32x4){0.f, 0.f, 0.f, 0.f};

    for (int kt = 0; kt < 512; kt += 64) {
        #pragma unroll
        for (int kc = 0; kc < 2; ++kc) {
            const int kg = kt + kc * 32 + koff;
            gl_lds16(&Xhb [(long)srow * 512 + kg], &stg[(0 * 2 + kc) * 2048 + wave * 512]);
            gl_lds16(&Xlb [(long)srow * 512 + kg], &stg[(1 * 2 + kc) * 2048 + wave * 512]);
            gl_lds16(&bthb[(long)srow * 512 + kg], &stg[(2 * 2 + kc) * 2048 + wave * 512]);
            gl_lds16(&btlb[(long)srow * 512 + kg], &stg[(3 * 2 + kc) * 2048 + wave * 512]);
        }
        __syncthreads();
        #pragma unroll
        for (int kc = 0; kc < 2; ++kc) {
            bf16x8 ah = *(const bf16x8*)&stg[(0 * 2 + kc) * 2048 + (wave * 16 + lr) * 32 + quad * 8];
            bf16x8 al = *(const bf16x8*)&stg[(1 * 2 + kc) * 2048 + (wave * 16 + lr) * 32 + quad * 8];
            #pragma unroll
            for (int j = 0; j < 4; ++j) {
                bf16x8 bh = *(const bf16x8*)&stg[(2 * 2 + kc) * 2048 + (j * 16 + lr) * 32 + quad * 8];
                bf16x8 bl = *(const bf16x8*)&stg[(3 * 2 + kc) * 2048 + (j * 16 + lr) * 32 + quad * 8];
                accx[j] = __builtin_amdgcn_mfma_f32_16x16x32_bf16(ah, bh, accx[j], 0, 0, 0);
                accx[j] = __builtin_amdgcn_mfma_f32_16x16x32_bf16(ah, bl, accx[j], 0, 0, 0);
                accx[j] = __builtin_amdgcn_mfma_f32_16x16x32_bf16(al, bh, accx[j], 0, 0, 0);
            }
        }
        __syncthreads();
    }

    float cnew[4][4]; // [j][reg]
    if (MODE == 1) {
        // denom = coef @ btb (split MFMA; coef A-frags direct from global fp32)
        f32x4 accd[4];
        #pragma unroll
        for (int j = 0; j < 4; ++j) accd[j] = (f32x4){0.f, 0.f, 0.f, 0.f};
        #pragma unroll
        for (int kk = 0; kk < 2; ++kk) {
            const float* cp = &coefB[(wave * 16 + lr) * 64 + kk * 32 + quad * 8];
            float4 cA = *(const float4*)cp;
            float4 cB = *(const float4*)(cp + 4);
            float cv[8] = {cA.x, cA.y, cA.z, cA.w, cB.x, cB.y, cB.z, cB.w};
            bf16x8 ah, al;
            #pragma unroll
            for (int e = 0; e < 8; ++e) {
                ushort_t h = f2bf(cv[e]);
                ((short*)&ah)[e] = (short)h;
                ((short*)&al)[e] = (short)f2bf(cv[e] - bf2f(h));
            }
            #pragma unroll
            for (int j = 0; j < 4; ++j) {
                bf16x8 bh = *(const bf16x8*)&gLh[(j * 16 + lr) * 72 + kk * 32 + quad * 8];
                bf16x8 bl = *(const bf16x8*)&gLl[(j * 16 + lr) * 72 + kk * 32 + quad * 8];
                accd[j] = __builtin_amdgcn_mfma_f32_16x16x32_bf16(ah, bh, accd[j], 0, 0, 0);
                accd[j] = __builtin_amdgcn_mfma_f32_16x16x32_bf16(ah, bl, accd[j], 0, 0, 0);
                accd[j] = __builtin_amdgcn_mfma_f32_16x16x32_bf16(al, bh, accd[j], 0, 0, 0);
            }
        }
        #pragma unroll
        for (int j = 0; j < 4; ++j)
            #pragma unroll
            for (int r = 0; r < 4; ++r) {
                float cold = coefB[(wave * 16 + quad * 4 + r) * 64 + j * 16 + lr];
                cnew[j][r] = cold * accx[j][r] / (accd[j][r] + NMF_EPS);
            }
    } else {
        #pragma unroll
        for (int r = 0; r < 4; ++r) {
            float m = fmaxf(fmaxf(accx[0][r], accx[1][r]), fmaxf(accx[2][r], accx[3][r]));
            #pragma unroll
            for (int off = 1; off < 16; off <<= 1) m = fmaxf(m, __shfl_xor(m, off, 64));
            float e[4], s = 0.f;
            #pragma unroll
            for (int j = 0; j < 4; ++j) { e[j] = __expf(accx[j][r] - m); s += e[j]; }
            #pragma unroll
            for (int off = 1; off < 16; off <<= 1) s += __shfl_xor(s, off, 64);
            float inv = 1.f / s;
            #pragma unroll
            for (int j = 0; j < 4; ++j) cnew[j][r] = e[j] * inv;
        }
    }

    #pragma unroll
    for (int j = 0; j < 4; ++j)
        #pragma unroll
        for (int r = 0; r < 4; ++r)
            coefB[(wave * 16 + quad * 4 + r) * 64 + j * 16 + lr] = cnew[j][r];

    if (MODE == 0) return;

    __syncthreads();  // btb dead; overlay ct on gL
    #pragma unroll
    for (int j = 0; j < 4; ++j)
        #pragma unroll
        for (int r = 0; r < 4; ++r) {
            const int nl = wave * 16 + quad * 4 + r;
            const int rr = j * 16 + lr;
            float v = cnew[j][r];
            ushort_t h = f2bf(v);
            gLh[rr * 72 + nl] = h;
            gLl[rr * 72 + nl] = f2bf(v - bf2f(h));
        }
    __syncthreads();
    for (int i = tid; i < 4096; i += 256) {
        const int r = i >> 6, nn = i & 63;
        cth[(long)b * 262144 + (long)r * 4096 + n0 + nn] = gLh[r * 72 + nn];
        ctl[(long)b * 262144 + (long)r * 4096 + n0 + nn] = gLl[r * 72 + nn];
    }
    // ctc Gram partials via MFMA
    f32x4 accc[4];
    #pragma unroll
    for (int j = 0; j < 4; ++j) accc[j] = (f32x4){0.f, 0.f, 0.f, 0.f};
    #pragma unroll
    for (int kk = 0; kk < 64; kk += 32) {
        bf16x8 ah = *(const bf16x8*)&gLh[(wave * 16 + lr) * 72 + kk + quad * 8];
        bf16x8 al = *(const bf16x8*)&gLl[(wave * 16 + lr) * 72 + kk + quad * 8];
        #pragma unroll
        for (int j = 0; j < 4; ++j) {
            bf16x8 bh = *(const bf16x8*)&gLh[(j * 16 + lr) * 72 + kk + quad * 8];
            bf16x8 bl = *(const bf16x8*)&gLl[(j * 16 + lr) * 72 + kk + quad * 8];
            accc[j] = __builtin_amdgcn_mfma_f32_16x16x32_bf16(ah, bh, accc[j], 0, 0, 0);
            accc[j] = __builtin_amdgcn_mfma_f32_16x16x32_bf16(ah, bl, accc[j], 0, 0, 0);
            accc[j] = __builtin_amdgcn_mfma_f32_16x16x32_bf16(al, bh, accc[j], 0, 0, 0);
        }
    }
    float* cp = ctc_part + ((long)blockIdx.x * Bcnt + b) * 4096;
    #pragma unroll
    for (int j = 0; j < 4; ++j)
        #pragma unroll
        for (int r = 0; r < 4; ++r)
            cp[(wave * 16 + quad * 4 + r) * 64 + j * 16 + lr] = accc[j][r];
}

// reduce ctc partials
__global__ __launch_bounds__(256) void ctc_reduce(const float* __restrict__ part,
                                                  float* __restrict__ ctc, int Bcnt)
{
    const int b = blockIdx.x >> 4;
    const int i = (blockIdx.x & 15) * 256 + threadIdx.x;
    float v = 0.f;
    #pragma unroll 8
    for (int c = 0; c < 64; ++c)
        v += part[((long)c * Bcnt + b) * 4096 + i];
    ctc[(long)b * 4096 + i] = v;
}

// xc split-K partials, BK=64: part[kc][b][c][r] = sum_{k chunk} X[c,k]*ct[r,k]
// grid (8, C/64, B)
__global__ __launch_bounds__(256) void xc_partial(
    const ushort_t* __restrict__ Ah, const ushort_t* __restrict__ Al, // X_dn [B][512][4096]
    const ushort_t* __restrict__ Bh, const ushort_t* __restrict__ Bl, // ct  [B][64][4096]
    float* __restrict__ part, int Bcnt)
{
    __shared__ ushort_t stg[8 * 2048];
    const int tid = threadIdx.x, wave = tid >> 6, lane = tid & 63;
    const int quad = lane >> 4, lr = lane & 15;
    const int batch = blockIdx.z;
    const int m0 = blockIdx.y * 64;
    const int k0 = blockIdx.x * 512;

    const ushort_t* Ab  = Ah + (long)batch * 2097152;
    const ushort_t* Alb = Al + (long)batch * 2097152;
    const ushort_t* Bb  = Bh + (long)batch * 262144;
    const ushort_t* Blb = Bl + (long)batch * 262144;

    const int srow = wave * 16 + (lane >> 2);
    const int koff = (lane & 3) * 8;

    f32x4 acc[4];
    #pragma unroll
    for (int j = 0; j < 4; ++j) acc[j] = (f32x4){0.f, 0.f, 0.f, 0.f};

    for (int kt = 0; kt < 512; kt += 64) {
        #pragma unroll
        for (int kc = 0; kc < 2; ++kc) {
            const int kg = k0 + kt + kc * 32 + koff;
            gl_lds16(&Ab [(long)(m0 + srow) * 4096 + kg], &stg[(0 * 2 + kc) * 2048 + wave * 512]);
            gl_lds16(&Alb[(long)(m0 + srow) * 4096 + kg], &stg[(1 * 2 + kc) * 2048 + wave * 512]);
            gl_lds16(&Bb [(long)srow * 4096 + kg], &stg[(2 * 2 + kc) * 2048 + wave * 512]);
            gl_lds16(&Blb[(long)srow * 4096 + kg], &stg[(3 * 2 + kc) * 2048 + wave * 512]);
        }
        __syncthreads();
        #pragma unroll
        for (int kc = 0; kc < 2; ++kc) {
            bf16x8 ah = *(const bf16x8*)&stg[(0 * 2 + kc) * 2048 + (wave * 16 + lr) * 32 + quad * 8];
            bf16x8 al = *(const bf16x8*)&stg[(1 * 2 + kc) * 2048 + (wave * 16 + lr) * 32 + quad * 8];
            #pragma unroll
            for (int j = 0; j < 4; ++j) {
                bf16x8 bh = *(const bf16x8*)&stg[(2 * 2 + kc) * 2048 + (j * 16 + lr) * 32 + quad * 8];
                bf16x8 bl = *(const bf16x8*)&stg[(3 * 2 + kc) * 2048 + (j * 16 + lr) * 32 + quad * 8];
                acc[j] = __builtin_amdgcn_mfma_f32_16x16x32_bf16(ah, bh, acc[j], 0, 0, 0);
                acc[j] = __builtin_amdgcn_mfma_f32_16x16x32_bf16(ah, bl, acc[j], 0, 0, 0);
                acc[j] = __builtin_amdgcn_mfma_f32_16x16x32_bf16(al, bh, acc[j], 0, 0, 0);
            }
        }
        __syncthreads();
    }

    float* Cb = part + ((long)blockIdx.x * Bcnt + batch) * 32768;
    #pragma unroll
    for (int j = 0; j < 4; ++j) {
        const int col = j * 16 + lr;
        #pragma unroll
        for (int r = 0; r < 4; ++r)
            Cb[(long)(m0 + wave * 16 + quad * 4 + r) * 64 + col] = acc[j][r];
    }
}

// =====================================================================
// Fused bases step. grid (C/64, B).
// MODE 0 (prep): bases -> bt hi/lo + btb Gram partials
// MODE 1 (full): reduce xc partials, mu-update bases, then bt + btb partials
// =====================================================================
template<int MODE>
__global__ __launch_bounds__(256) void bases_step(
    const float* __restrict__ xc_part,   // [8][B][512][64]
    const float* __restrict__ ctc,       // [B][64][64]
    float* __restrict__ bases,           // [B][512][64]
    ushort_t* __restrict__ bth, ushort_t* __restrict__ btl, // [B][64][512]
    float* __restrict__ btb_part,        // [8][B][4096]
    int Bcnt)
{
    __shared__ char smem[16640 * 2 + 18432];
    float* bnL  = (float*)smem;                  // [64][65]
    float* ctcL = (float*)(smem + 16640);        // [64][65]
    ushort_t* btLh = (ushort_t*)(smem + 33280);  // [64][72]
    ushort_t* btLl = btLh + 64 * 72;
    float* basesL = (float*)(smem + 33280);      // overlays btL (phase 1 only)

    const int b = blockIdx.y, c0 = blockIdx.x * 64;
    const int tid = threadIdx.x;
    float* basesB = bases + (long)b * 32768 + (long)c0 * 64;

    if (MODE == 1) {
        for (int i = tid; i < 4096; i += 256) {
            const int c = i >> 6, r = i & 63;
            basesL[c * 65 + r] = basesB[i];
            ctcL[c * 65 + r]   = ctc[(long)b * 4096 + i];
            float v = 0.f;
            #pragma unroll
            for (int s0 = 0; s0 < 8; ++s0)
                v += xc_part[((long)s0 * Bcnt + b) * 32768 + (long)(c0 + c) * 64 + r];
            bnL[c * 65 + r] = v;
        }
        __syncthreads();
        for (int i = tid; i < 4096; i += 256) {
            const int c = i >> 6, r = i & 63;
            float denom = 0.f;
            #pragma unroll 8
            for (int s = 0; s < 64; ++s)
                denom = fmaf(basesL[c * 65 + s], ctcL[s * 65 + r], denom);
            float bnew = basesL[c * 65 + r] * bnL[c * 65 + r] / (denom + NMF_EPS);
            bnL[c * 65 + r] = bnew;
            basesB[i] = bnew;
        }
        __syncthreads();
    } else {
        for (int i = tid; i < 4096; i += 256)
            bnL[(i >> 6) * 65 + (i & 63)] = basesB[i];
        __syncthreads();
    }

    for (int i = tid; i < 4096; i += 256) {
        const int r = i >> 6, cc = i & 63;
        float v = bnL[cc * 65 + r];
        ushort_t h = f2bf(v);
        ushort_t l = f2bf(v - bf2f(h));
        btLh[r * 72 + cc] = h;
        btLl[r * 72 + cc] = l;
        bth[(long)b * 32768 + (long)r * 512 + c0 + cc] = h;
        btl[(long)b * 32768 + (long)r * 512 + c0 + cc] = l;
    }
    __syncthreads();

    const int wave = tid >> 6, lane = tid & 63;
    const int quad = lane >> 4, lr = lane & 15;
    f32x4 acg[4];
    #pragma unroll
    for (int j = 0; j < 4; ++j) acg[j] = (f32x4){0.f, 0.f, 0.f, 0.f};
    #pragma unroll
    for (int kk = 0; kk < 64; kk += 32) {
        bf16x8 ah = *(const bf16x8*)&btLh[(wave * 16 + lr) * 72 + kk + quad * 8];
        bf16x8 al = *(const bf16x8*)&btLl[(wave * 16 + lr) * 72 + kk + quad * 8];
        #pragma unroll
        for (int j = 0; j < 4; ++j) {
            bf16x8 bh = *(const bf16x8*)&btLh[(j * 16 + lr) * 72 + kk + quad * 8];
            bf16x8 bl = *(const bf16x8*)&btLl[(j * 16 + lr) * 72 + kk + quad * 8];
            acg[j] = __builtin_amdgcn_mfma_f32_16x16x32_bf16(ah, bh, acg[j], 0, 0, 0);
            acg[j] = __builtin_amdgcn_mfma_f32_16x16x32_bf16(ah, bl, acg[j], 0, 0, 0);
            acg[j] = __builtin_amdgcn_mfma_f32_16x16x32_bf16(al, bh, acg[j], 0, 0, 0);
        }
    }
    float* gp = btb_part + ((long)blockIdx.x * Bcnt + b) * 4096;
    #pragma unroll
    for (int j = 0; j < 4; ++j)
        #pragma unroll
        for (int r = 0; r < 4; ++r)
            gp[(wave * 16 + quad * 4 + r) * 64 + j * 16 + lr] = acg[j][r];
}

// =====================================================================
// fp32 tiled GEMM (cheese ops only): EPI 0 plain; 4 relu(+bias)->bf16 [n][m]
// =====================================================================
constexpr int BM = 64, BN = 64, BK = 16;

template<int ALAY, int BLAY, int EPI>
__global__ __launch_bounds__(256) void gemm_kernel(
    const float* __restrict__ A, const float* __restrict__ B, float* __restrict__ C,
    int Kchunk, int kchunks,
    int lda, int ldb, int ldc,
    long sA, long sB, long sC,
    const float* __restrict__ bias)
{
    __shared__ float As[BK][BM + 4];
    __shared__ float Bs[BK][BN + 4];

    const int batch = blockIdx.z;
    const float* Ab = A + (long)batch * sA;
    const float* Bb = B + (long)batch * sB;

    const int m0  = blockIdx.y * BM;
    const int n0  = blockIdx.x * BN;
    const int tid = threadIdx.x;
    const int ty  = tid >> 4, tx = tid & 15;

    float acc[4][4] = {};

    for (int kt = 0; kt < Kchunk; kt += BK) {
        if (ALAY == 0) {
            const int m = tid >> 2, k4 = (tid & 3) << 2;
            float4 v = *(const float4*)&Ab[(long)(m0 + m) * lda + (kt + k4)];
            As[k4 + 0][m] = v.x; As[k4 + 1][m] = v.y;
            As[k4 + 2][m] = v.z; As[k4 + 3][m] = v.w;
        } else {
            const int k = tid >> 4, m4 = (tid & 15) << 2;
            float4 v = *(const float4*)&Ab[(long)(kt + k) * lda + (m0 + m4)];
            *(float4*)&As[k][m4] = v;
        }
        if (BLAY == 0) {
            const int k = tid >> 4, n4 = (tid & 15) << 2;
            float4 v = *(const float4*)&Bb[(long)(kt + k) * ldb + (n0 + n4)];
            *(float4*)&Bs[k][n4] = v;
        } else {
            const int n = tid >> 2, k4 = (tid & 3) << 2;
            float4 v = *(const float4*)&Bb[(long)(n0 + n) * ldb + (kt + k4)];
            Bs[k4 + 0][n] = v.x; Bs[k4 + 1][n] = v.y;
            Bs[k4 + 2][n] = v.z; Bs[k4 + 3][n] = v.w;
        }
        __syncthreads();
        #pragma unroll
        for (int k = 0; k < BK; ++k) {
            float4 a4 = *(const float4*)&As[k][ty << 2];
            float4 b4 = *(const float4*)&Bs[k][tx << 2];
            float av[4] = {a4.x, a4.y, a4.z, a4.w};
            float bv[4] = {b4.x, b4.y, b4.z, b4.w};
            #pragma unroll
            for (int i = 0; i < 4; ++i)
                #pragma unroll
                for (int j = 0; j < 4; ++j)
                    acc[i][j] = fmaf(av[i], bv[j], acc[i][j]);
        }
        __syncthreads();
    }

    const int mb = m0 + (ty << 2), nb = n0 + (tx << 2);
    if (EPI == 4) {
        ushort_t* Cu = (ushort_t*)C + (long)batch * sC;
        #pragma unroll
        for (int j = 0; j < 4; ++j) {
            ushort_t pk[4];
            #pragma unroll
            for (int i = 0; i < 4; ++i)
                pk[i] = f2bf(fmaxf(acc[i][j] + bias[mb + i], 0.f));
            *(ushort4*)&Cu[(long)(nb + j) * ldc + mb] =
                make_ushort4(pk[0], pk[1], pk[2], pk[3]);
        }
    } else {
        float* Cb = C + (long)batch * sC;
        #pragma unroll
        for (int i = 0; i < 4; ++i) {
            float4 o = make_float4(acc[i][0], acc[i][1], acc[i][2], acc[i][3]);
            *(float4*)&Cb[(long)(mb + i) * ldc + nb] = o;
        }
    }
}

// ---------- casts / transposes ----------
__global__ __launch_bounds__(256) void cast_x_t(const float* __restrict__ x,
                                                ushort_t* __restrict__ hi,
                                                ushort_t* __restrict__ lo)
{
    __shared__ float t[64][65];
    const int b = blockIdx.z, c0 = blockIdx.y * 64, n0 = blockIdx.x * 64;
    const int tid = threadIdx.x, tx = tid & 63, ty = tid >> 6;
    const float* xb = x + (long)b * 512 * 4096;
    #pragma unroll 4
    for (int s = ty; s < 64; s += 4)
        t[s][tx] = xb[(long)(c0 + s) * 4096 + n0 + tx];
    __syncthreads();
    #pragma unroll 4
    for (int s = ty; s < 64; s += 4) {
        float v = t[tx][s];
        long idx = (long)b * 2097152 + (long)(n0 + s) * 512 + c0 + tx;
        ushort_t h = f2bf(v);
        hi[idx] = h;
        lo[idx] = f2bf(v - bf2f(h));
    }
}

__global__ __launch_bounds__(256) void nd2dn(const ushort_t* __restrict__ hi,
                                             const ushort_t* __restrict__ lo,
                                             ushort_t* __restrict__ dhi,
                                             ushort_t* __restrict__ dlo)
{
    __shared__ unsigned int t[64][65];
    const int b = blockIdx.z, n0 = blockIdx.x * 64, c0 = blockIdx.y * 64;
    const int tx = threadIdx.x & 63, ty = threadIdx.x >> 6;
    const long base = (long)b * 2097152;
    #pragma unroll 4
    for (int s = ty; s < 64; s += 4) {
        long idx = base + (long)(n0 + s) * 512 + c0 + tx;
        t[s][tx] = (unsigned)hi[idx] | ((unsigned)lo[idx] << 16);
    }
    __syncthreads();
    #pragma unroll 4
    for (int s = ty; s < 64; s += 4) {
        unsigned v = t[tx][s];
        long idx = base + (long)(c0 + s) * 4096 + n0 + tx;
        dhi[idx] = (ushort_t)(v & 0xffffu);
        dlo[idx] = (ushort_t)(v >> 16);
    }
}

__global__ void cast_w_split(const float* __restrict__ w, ushort_t* __restrict__ hi,
                             ushort_t* __restrict__ lo, int n)
{
    int i = blockIdx.x * 256 + threadIdx.x;
    if (i < n) {
        float v = w[i];
        ushort_t h = f2bf(v);
        hi[i] = h;
        lo[i] = f2bf(v - bf2f(h));
    }
}

__global__ void cast_w_plain(const float* __restrict__ w, ushort_t* __restrict__ o, int n)
{
    int i = blockIdx.x * 256 + threadIdx.x;
    if (i < n) o[i] = f2bf(w[i]);
}

__global__ __launch_bounds__(1024) void l2norm_kernel(const float* __restrict__ b0,
                                                      float* __restrict__ bases)
{
    __shared__ float part[16][64];
    const int b = blockIdx.x;
    const int tid = threadIdx.x;
    const int r = tid & 63, slice = tid >> 6;
    const float* src = b0 + (long)b * 512 * 64;
    float* dst = bases + (long)b * 512 * 64;
    float s = 0.f;
    #pragma unroll 4
    for (int d = slice; d < 512; d += 16) {
        float v = src[d * 64 + r];
        s = fmaf(v, v, s);
    }
    part[slice][r] = s;
    __syncthreads();
    if (slice == 0) {
        float t = 0.f;
        #pragma unroll
        for (int i = 0; i < 16; ++i) t += part[i][r];
        part[0][r] = 1.0f / fmaxf(sqrtf(t), 1e-12f);
    }
    __syncthreads();
    const float inv = part[0][r];
    #pragma unroll 4
    for (int d = slice; d < 512; d += 16)
        dst[d * 64 + r] = src[d * 64 + r] * inv;
}

extern "C" void kernel_launch(void* const* d_in, const int* in_sizes, int n_in,
                              void* d_out, int out_size, void* d_ws, size_t ws_size,
                              hipStream_t stream)
{
    const float* x_in     = (const float*)d_in[0];
    const float* bases0   = (const float*)d_in[1];
    const float* w_lower  = (const float*)d_in[2];
    const float* b_lower  = (const float*)d_in[3];
    const float* w_cheese = (const float*)d_in[4];
    const float* b_cheese = (const float*)d_in[5];
    const float* w_upper  = (const float*)d_in[6];
    const float* csc      = (const float*)d_in[7];
    const float* cham     = (const float*)d_in[8];
    float* out = (float*)d_out;

    const int B = 8, C = 512, N = 4096, R = 64;
    const long sCN = (long)C * N;
    const long sNC = (long)N * C;
    const long sNR = (long)N * R, sCR = (long)C * R;

    // ---- workspace layout (bytes, ~141 MB) ----
    char* w = (char*)d_ws;
    ushort_t* X_nd_hi  = (ushort_t*)w;  w += 33554432;  // [B,N,C]
    ushort_t* xt_hi    = (ushort_t*)w;  w += 33554432;  // x^T; later X_dn_hi
    ushort_t* xt_lo    = (ushort_t*)w;  w += 33554432;  // x^T; later X_dn_lo
    float*    coef     = (float*)w;     w += 8388608;   // [B,N,R]
    ushort_t* ct_hi    = (ushort_t*)w;  w += 4194304;   // [B,R,N]
    ushort_t* ct_lo    = (ushort_t*)w;  w += 4194304;
    float*    ctc_part = (float*)w;     w += 8388608;   // [64][B][4096]
    float*    xc_part  = (float*)w;     w += 8388608;   // [8][B][512][64]
    float*    btb_part = (float*)w;     w += 1048576;   // [8][B][4096]
    float*    bases    = (float*)w;     w += 1048576;   // [B,C,R]
    float*    WcB      = (float*)w;     w += 1048576;   // [B,C,R]
    float*    ctc      = (float*)w;     w += 131072;    // [B,R,R]
    ushort_t* bt_hi    = (ushort_t*)w;  w += 524288;    // [B,R,C]
    ushort_t* bt_lo    = (ushort_t*)w;  w += 524288;
    ushort_t* wl_hi    = (ushort_t*)w;  w += 524288;
    ushort_t* wl_lo    = (ushort_t*)w;  w += 524288;
    ushort_t* w_up     = (ushort_t*)w;  w += 524288;

    ushort_t* X_nd_lo  = (ushort_t*)d_out;  // dead before final out write
    ushort_t* X_dn_hi  = xt_hi;
    ushort_t* X_dn_lo  = xt_lo;
    ushort_t* cheese_t = X_nd_hi;           // X_nd dead after final coef_step

    const dim3 blk(256);

    // init
    l2norm_kernel<<<dim3(B), dim3(1024), 0, stream>>>(bases0, bases);
    bases_step<0><<<dim3(C / 64, B), blk, 0, stream>>>(
        nullptr, nullptr, bases, bt_hi, bt_lo, btb_part, B);
    cast_w_split<<<dim3(1024), blk, 0, stream>>>(w_lower, wl_hi, wl_lo, C * C);
    cast_w_plain<<<dim3(1024), blk, 0, stream>>>(w_upper, w_up, C * C);
    cast_x_t<<<dim3(N / 64, C / 64, B), blk, 0, stream>>>(x_in, xt_hi, xt_lo);

    // X = relu(w_lower @ x + b_lower) -> bf16 hi/lo [n][c]
    mfma_gemm<1, 2><<<dim3(N / 128, C / 128, B), blk, 0, stream>>>(
        wl_hi, wl_lo, xt_hi, xt_lo, nullptr, X_nd_hi, X_nd_lo,
        C, N, C, sNC, sNC, b_lower, nullptr, 0L, nullptr, nullptr);
    nd2dn<<<dim3(N / 64, C / 64, B), blk, 0, stream>>>(X_nd_hi, X_nd_lo, X_dn_hi, X_dn_lo);

    // coef init (softmax)
    coef_step<0><<<dim3(N / 64, B), blk, 0, stream>>>(
        X_nd_hi, X_nd_lo, bt_hi, bt_lo, btb_part, coef, ct_hi, ct_lo, ctc_part, B);

    for (int step = 0; step < 6; ++step) {
        coef_step<1><<<dim3(N / 64, B), blk, 0, stream>>>(
            X_nd_hi, X_nd_lo, bt_hi, bt_lo, btb_part, coef, ct_hi, ct_lo, ctc_part, B);
        ctc_reduce<<<dim3(B * 16), blk, 0, stream>>>(ctc_part, ctc, B);
        xc_partial<<<dim3(8, C / 64, B), blk, 0, stream>>>(
            X_dn_hi, X_dn_lo, ct_hi, ct_lo, xc_part, B);
        bases_step<1><<<dim3(C / 64, B), blk, 0, stream>>>(
            xc_part, ctc, bases, bt_hi, bt_lo, btb_part, B);
    }

    // final differentiable coef refinement
    coef_step<1><<<dim3(N / 64, B), blk, 0, stream>>>(
        X_nd_hi, X_nd_lo, bt_hi, bt_lo, btb_part, coef, ct_hi, ct_lo, ctc_part, B);

    // cheese via associativity
    gemm_kernel<0, 0, 0><<<dim3(1, C / BM, B), blk, 0, stream>>>(
        w_cheese, bases, WcB, C, 1, C, R, R, 0L, sCR, sCR, nullptr);
    gemm_kernel<0, 1, 4><<<dim3(N / BN, C / BM, B), blk, 0, stream>>>(
        WcB, coef, (float*)cheese_t, R, 1, R, R, C, sCR, sNR, sNC, b_cheese);

    // out = relu(ham * (w_upper @ cheese) + sc * x)
    mfma_gemm<0, 3><<<dim3(N / 128, C / 128, B), blk, 0, stream>>>(
        w_up, nullptr, cheese_t, nullptr, out, nullptr, nullptr,
        C, N, C, sNC, sCN, nullptr, x_in, sCN, cham, csc);
}